// Round 1
// baseline (4193.538 us; speedup 1.0000x reference)
//
#include <hip/hip_runtime.h>
#include <stdint.h>

typedef unsigned short u16;
typedef __attribute__((ext_vector_type(8))) short bf16x8;
typedef __attribute__((ext_vector_type(4))) float f32x4;

static __device__ __forceinline__ u16 f2b(float f) {
  uint32_t u = __builtin_bit_cast(uint32_t, f);
  u += 0x7fffu + ((u >> 16) & 1u);
  return (u16)(u >> 16);
}
static __device__ __forceinline__ float b2f(u16 h) {
  uint32_t u = ((uint32_t)h) << 16;
  return __builtin_bit_cast(float, u);
}

// ---------------- generic f32 -> bf16 convert ----------------
__global__ void f2b_kernel(const float* __restrict__ in, u16* __restrict__ out, int n) {
  int i = blockIdx.x * 256 + threadIdx.x;
  if (i < n) out[i] = f2b(in[i]);
}

// ---------------- embedding + PE + LayerNorm ----------------
__global__ __launch_bounds__(256) void embed_ln_kernel(
    const float* __restrict__ x, const float* __restrict__ rtg,
    const float* __restrict__ Wse, const float* __restrict__ bse,
    const float* __restrict__ Wre, const float* __restrict__ bre,
    const float* __restrict__ lnw, const float* __restrict__ lnb,
    float* __restrict__ h) {
  const int tok = blockIdx.x;           // b*1024 + l
  const int l = tok & 1023;
  const int d = threadIdx.x;            // 0..255
  __shared__ float xs[128];
  __shared__ float rs[4], rq[4];
  if (d < 128) xs[d] = x[(size_t)tok * 128 + d];
  __syncthreads();
  const float* wrow = Wse + (size_t)d * 128;
  float se = bse[d];
#pragma unroll
  for (int j = 0; j < 128; j += 4) {
    float4 w4 = *(const float4*)(wrow + j);
    se += xs[j] * w4.x + xs[j + 1] * w4.y + xs[j + 2] * w4.z + xs[j + 3] * w4.w;
  }
  float re = bre[d] + rtg[tok] * Wre[d];
  // positional encoding: PE[l,dd]; dd even: sin(l*div), odd: cos(l*div), div=exp(-(2*(dd>>1))*ln(1e4)/512)
  const float c = -9.210340371976184f / 512.f;
  float div0 = expf((float)(2 * (d >> 1)) * c);
  float pe0 = (d & 1) ? cosf((float)l * div0) : sinf((float)l * div0);
  int d2 = d + 256;
  float div1 = expf((float)(2 * (d2 >> 1)) * c);
  float pe1 = (d2 & 1) ? cosf((float)l * div1) : sinf((float)l * div1);
  float h0 = se + pe0, h1 = re + pe1;
  float s = h0 + h1, q = h0 * h0 + h1 * h1;
#pragma unroll
  for (int o = 32; o; o >>= 1) { s += __shfl_xor(s, o); q += __shfl_xor(q, o); }
  if ((d & 63) == 0) { rs[d >> 6] = s; rq[d >> 6] = q; }
  __syncthreads();
  float S = rs[0] + rs[1] + rs[2] + rs[3];
  float Q = rq[0] + rq[1] + rq[2] + rq[3];
  float mean = S * (1.f / 512.f);
  float var = Q * (1.f / 512.f) - mean * mean;
  float rstd = rsqrtf(var + 1e-5f);
  size_t base = (size_t)tok * 512;
  h[base + d]  = (h0 - mean) * rstd * lnw[d]  + lnb[d];
  h[base + d2] = (h1 - mean) * rstd * lnw[d2] + lnb[d2];
}

// ---------------- residual add + RMSNorm -> bf16 ----------------
__global__ __launch_bounds__(256) void resid_rms_kernel(
    const float* __restrict__ hin, float* __restrict__ residual,
    const float* __restrict__ w, u16* __restrict__ outb, int first) {
  const int tok = blockIdx.x;
  const int t = threadIdx.x;
  __shared__ float rq[4];
  size_t base = (size_t)tok * 512;
  float v0 = hin[base + t], v1 = hin[base + t + 256];
  if (!first) { v0 += residual[base + t]; v1 += residual[base + t + 256]; }
  residual[base + t] = v0;
  residual[base + t + 256] = v1;
  float q = v0 * v0 + v1 * v1;
#pragma unroll
  for (int o = 32; o; o >>= 1) q += __shfl_xor(q, o);
  if ((t & 63) == 0) rq[t >> 6] = q;
  __syncthreads();
  float Q = rq[0] + rq[1] + rq[2] + rq[3];
  float scale = rsqrtf(Q * (1.f / 512.f) + 1e-5f);
  outb[base + t]       = f2b(v0 * scale * w[t]);
  outb[base + t + 256] = f2b(v1 * scale * w[t + 256]);
}

// ---------------- MFMA GEMM: C[M,N] = A[M,K] * Bw[N,K]^T ----------------
// A, Bw bf16 row-major. EPI: 0=f32 store, 1=bf16 store, 2=bias+relu->bf16, 3=bias->f32
template <int BM, int BN, int WM, int WN, int EPI>
__global__ __launch_bounds__(256) void gemm_bt(
    const u16* __restrict__ A, const u16* __restrict__ Bw,
    float* __restrict__ Cf, u16* __restrict__ Cb,
    const float* __restrict__ bias, int M, int N, int K) {
  constexpr int MF = BM / (WM * 16);
  constexpr int NF = BN / (WN * 16);
  constexpr int NCA = (BM * 4) / 256;   // 16B chunks per thread for A tile (BMx32 bf16)
  constexpr int NCB = (BN * 4) / 256;
  __shared__ __align__(16) u16 lA[BM * 32];
  __shared__ __align__(16) u16 lB[BN * 32];
  const int tid = threadIdx.x;
  const int lane = tid & 63;
  const int wv = tid >> 6;
  const int wr = wv / WN, wc = wv % WN;
  const int m0 = blockIdx.x * BM, n0 = blockIdx.y * BN;

  f32x4 acc[MF][NF];
#pragma unroll
  for (int i = 0; i < MF; ++i)
#pragma unroll
    for (int j = 0; j < NF; ++j) acc[i][j] = (f32x4){0.f, 0.f, 0.f, 0.f};

  const int srow = tid >> 2, sck = tid & 3;  // staging: 4 chunks of 8 bf16 per 32-wide row
  const u16* Ag = A + (size_t)(m0 + srow) * K + sck * 8;
  const u16* Bg = Bw + (size_t)(n0 + srow) * K + sck * 8;

  for (int k0 = 0; k0 < K; k0 += 32) {
    uint4 ra[NCA], rb[NCB];
#pragma unroll
    for (int it = 0; it < NCA; ++it)
      ra[it] = *(const uint4*)(Ag + (size_t)it * 64 * K + k0);
#pragma unroll
    for (int it = 0; it < NCB; ++it)
      rb[it] = *(const uint4*)(Bg + (size_t)it * 64 * K + k0);
    __syncthreads();
#pragma unroll
    for (int it = 0; it < NCA; ++it)
      *(uint4*)(&lA[(it * 256 + tid) * 8]) = ra[it];
#pragma unroll
    for (int it = 0; it < NCB; ++it)
      *(uint4*)(&lB[(it * 256 + tid) * 8]) = rb[it];
    __syncthreads();
    bf16x8 af[MF], bfr[NF];
    const int koff = (lane >> 4) * 8;
#pragma unroll
    for (int mi = 0; mi < MF; ++mi) {
      int r = wr * (MF * 16) + mi * 16 + (lane & 15);
      af[mi] = *(const bf16x8*)(&lA[r * 32 + koff]);
    }
#pragma unroll
    for (int ni = 0; ni < NF; ++ni) {
      int r = wc * (NF * 16) + ni * 16 + (lane & 15);
      bfr[ni] = *(const bf16x8*)(&lB[r * 32 + koff]);
    }
#pragma unroll
    for (int mi = 0; mi < MF; ++mi)
#pragma unroll
      for (int ni = 0; ni < NF; ++ni)
        acc[mi][ni] = __builtin_amdgcn_mfma_f32_16x16x32_bf16(af[mi], bfr[ni], acc[mi][ni], 0, 0, 0);
  }

  const int rbase = (lane >> 4) * 4;
  const int cbase = lane & 15;
#pragma unroll
  for (int mi = 0; mi < MF; ++mi) {
#pragma unroll
    for (int ni = 0; ni < NF; ++ni) {
      int row = m0 + wr * (MF * 16) + mi * 16 + rbase;
      int col = n0 + wc * (NF * 16) + ni * 16 + cbase;
      float bv = (EPI >= 2) ? bias[col] : 0.f;
#pragma unroll
      for (int r = 0; r < 4; ++r) {
        float v = acc[mi][ni][r] + bv;
        if (EPI == 2) v = fmaxf(v, 0.f);
        size_t idx = (size_t)(row + r) * N + col;
        if (EPI == 1 || EPI == 2) Cb[idx] = f2b(v);
        else Cf[idx] = v;
      }
    }
  }
}

// ---------------- causal depthwise conv(K=4) + silu ----------------
__global__ __launch_bounds__(256) void conv_silu_kernel(
    const u16* __restrict__ xz, const float* __restrict__ cw,
    const float* __restrict__ cb, float* __restrict__ xc, u16* __restrict__ xcb) {
  int idx = blockIdx.x * 256 + threadIdx.x;   // (b,t,d) over 4*1024*1024
  int d = idx & 1023;
  int t = (idx >> 10) & 1023;
  int token = idx >> 10;
  float4 w4 = *(const float4*)(cw + (size_t)d * 4);
  const float wk[4] = {w4.x, w4.y, w4.z, w4.w};
  float s = cb[d];
  const u16* xx = xz + (size_t)(token - t) * 2048 + d;  // seq start for this b, xx part (col<1024)
#pragma unroll
  for (int k = 0; k < 4; ++k) {
    int tt = t - 3 + k;
    if (tt >= 0) s += wk[k] * b2f(xx[(size_t)tt * 2048]);
  }
  float sl = s / (1.f + expf(-s));
  xc[idx] = sl;
  xcb[idx] = f2b(sl);
}

// ---------------- dt = softplus(dbc[:, :32] @ dpw^T + dpb) ----------------
__global__ __launch_bounds__(256) void dt_kernel(
    const float* __restrict__ dbc, const float* __restrict__ dpw,
    const float* __restrict__ dpb, float* __restrict__ dtout) {
  const int tok = blockIdx.x;
  const int th = threadIdx.x;
  __shared__ float s[32];
  if (th < 32) s[th] = dbc[(size_t)tok * 64 + th];
  __syncthreads();
#pragma unroll
  for (int q = 0; q < 4; ++q) {
    int dd = th + q * 256;
    const float* wr = dpw + (size_t)dd * 32;
    float a = dpb[dd];
#pragma unroll
    for (int j = 0; j < 32; j += 4) {
      float4 w4 = *(const float4*)(wr + j);
      a += s[j] * w4.x + s[j + 1] * w4.y + s[j + 2] * w4.z + s[j + 3] * w4.w;
    }
    float sp = (a > 20.f) ? a : logf(1.f + expf(a));
    dtout[(size_t)tok * 1024 + dd] = sp;
  }
}

// ---------------- selective scan + D-skip + silu(z) gating -> bf16 ----------------
// lane layout: n = lane&15 (state), dl = lane>>4 (4 channels per wave)
__global__ __launch_bounds__(256) void scan_kernel(
    const float* __restrict__ dt, const float* __restrict__ xc,
    const float* __restrict__ dbc, const u16* __restrict__ xz,
    const float* __restrict__ Alog, const float* __restrict__ Dp,
    u16* __restrict__ yg) {
  const int gid = blockIdx.x;        // 256 blocks
  const int b = gid >> 6;            // 4
  const int dblk = gid & 63;         // 64 -> d base = dblk*16
  const int lane = threadIdx.x & 63;
  const int wv = threadIdx.x >> 6;
  const int n = lane & 15;
  const int dl = lane >> 4;
  const int d = dblk * 16 + wv * 4 + dl;
  const float A2 = -expf(Alog[(size_t)d * 16 + n]) * 1.4426950408889634f;  // fold log2(e)
  const float Dd = Dp[d];
  float hc = 0.f;
  size_t tok = (size_t)b * 1024;
  for (int t = 0; t < 1024; ++t, ++tok) {
    float dtv = dt[tok * 1024 + d];
    float xcv = xc[tok * 1024 + d];
    float Bn = dbc[tok * 64 + 32 + n];
    float Cn = dbc[tok * 64 + 48 + n];
    float e = exp2f(dtv * A2);
    hc = e * hc + (dtv * xcv) * Bn;
    float y = hc * Cn;
    y += __shfl_xor(y, 1);
    y += __shfl_xor(y, 2);
    y += __shfl_xor(y, 4);
    y += __shfl_xor(y, 8);
    if (n == 0) {
      float z = b2f(xz[tok * 2048 + 1024 + d]);
      float g = z / (1.f + expf(-z));
      yg[tok * 1024 + d] = f2b((y + Dd * xcv) * g);
    }
  }
}

// ---------------- reward head: out = t1r @ ro_w2^T + b (N=1) ----------------
__global__ __launch_bounds__(256) void reward_head_kernel(
    const u16* __restrict__ t1r, const float* __restrict__ w2,
    const float* __restrict__ b2, float* __restrict__ outr) {
  int tok = blockIdx.x * 4 + (threadIdx.x >> 6);
  int lane = threadIdx.x & 63;
  float s = 0.f;
#pragma unroll
  for (int j = 0; j < 256; j += 64) s += b2f(t1r[(size_t)tok * 256 + j + lane]) * w2[j + lane];
#pragma unroll
  for (int o = 32; o; o >>= 1) s += __shfl_xor(s, o);
  if (lane == 0) outr[tok] = s + b2[0];
}

extern "C" void kernel_launch(void* const* d_in, const int* in_sizes, int n_in,
                              void* d_out, int out_size, void* d_ws, size_t ws_size,
                              hipStream_t stream) {
  const float* x    = (const float*)d_in[0];
  const float* rtg  = (const float*)d_in[1];
  const float* Wse  = (const float*)d_in[2];
  const float* bse  = (const float*)d_in[3];
  const float* Wre  = (const float*)d_in[4];
  const float* bre  = (const float*)d_in[5];
  const float* lnw  = (const float*)d_in[6];
  const float* lnb  = (const float*)d_in[7];
  const float* ipw  = (const float*)d_in[8];
  const float* cw   = (const float*)d_in[9];
  const float* cb   = (const float*)d_in[10];
  const float* xpw  = (const float*)d_in[11];
  const float* dpw  = (const float*)d_in[12];
  const float* dpb  = (const float*)d_in[13];
  const float* Alog = (const float*)d_in[14];
  const float* Dp   = (const float*)d_in[15];
  const float* opw  = (const float*)d_in[16];
  const float* nw   = (const float*)d_in[17];
  const float* nfw  = (const float*)d_in[18];
  const float* sow1 = (const float*)d_in[19];
  const float* sob1 = (const float*)d_in[20];
  const float* sow2 = (const float*)d_in[21];
  const float* sob2 = (const float*)d_in[22];
  const float* row1 = (const float*)d_in[23];
  const float* rob1 = (const float*)d_in[24];
  const float* row2 = (const float*)d_in[25];
  const float* rob2 = (const float*)d_in[26];
  (void)in_sizes; (void)n_in; (void)out_size; (void)ws_size;

  char* wsp = (char*)d_ws;
  size_t off = 0;
  auto alloc = [&](size_t bytes) -> void* {
    off = (off + 255) & ~(size_t)255;
    void* p = wsp + off;
    off += bytes;
    return p;
  };
  const int TOK = 4096;
  float* h     = (float*)alloc((size_t)TOK * 512 * 4);
  float* resid = (float*)alloc((size_t)TOK * 512 * 4);
  u16* hn      = (u16*)alloc((size_t)TOK * 512 * 2);
  u16* xzb     = (u16*)alloc((size_t)TOK * 2048 * 2);
  float* xcf   = (float*)alloc((size_t)TOK * 1024 * 4);
  u16* xcb     = (u16*)alloc((size_t)TOK * 1024 * 2);   // also reused as gated-y bf16
  float* dbc   = (float*)alloc((size_t)TOK * 64 * 4);
  float* dtf   = (float*)alloc((size_t)TOK * 1024 * 4);
  u16* ipwb    = (u16*)alloc((size_t)4 * 2048 * 512 * 2);
  u16* xpwb    = (u16*)alloc((size_t)4 * 64 * 1024 * 2);
  u16* opwb    = (u16*)alloc((size_t)4 * 512 * 1024 * 2);
  u16* sow1b   = (u16*)alloc((size_t)256 * 512 * 2);
  u16* sow2b   = (u16*)alloc((size_t)128 * 256 * 2);
  u16* row1b   = (u16*)alloc((size_t)256 * 512 * 2);
  u16* t1s     = (u16*)alloc((size_t)TOK * 256 * 2);
  u16* t1r     = (u16*)alloc((size_t)TOK * 256 * 2);

  auto cvt = [&](const float* src, u16* dst, int n) {
    f2b_kernel<<<(n + 255) / 256, 256, 0, stream>>>(src, dst, n);
  };
  cvt(ipw, ipwb, 4 * 2048 * 512);
  cvt(xpw, xpwb, 4 * 64 * 1024);
  cvt(opw, opwb, 4 * 512 * 1024);
  cvt(sow1, sow1b, 256 * 512);
  cvt(sow2, sow2b, 128 * 256);
  cvt(row1, row1b, 256 * 512);

  embed_ln_kernel<<<TOK, 256, 0, stream>>>(x, rtg, Wse, bse, Wre, bre, lnw, lnb, h);

  for (int i = 0; i < 4; ++i) {
    resid_rms_kernel<<<TOK, 256, 0, stream>>>(h, resid, nw + i * 512, hn, i == 0);
    gemm_bt<128, 128, 2, 2, 1><<<dim3(32, 16), 256, 0, stream>>>(
        hn, ipwb + (size_t)i * 2048 * 512, nullptr, xzb, nullptr, 4096, 2048, 512);
    conv_silu_kernel<<<TOK * 1024 / 256, 256, 0, stream>>>(
        xzb, cw + (size_t)i * 4096, cb + i * 1024, xcf, xcb);
    gemm_bt<128, 64, 2, 2, 0><<<dim3(32, 1), 256, 0, stream>>>(
        xcb, xpwb + (size_t)i * 64 * 1024, dbc, nullptr, nullptr, 4096, 64, 1024);
    dt_kernel<<<TOK, 256, 0, stream>>>(dbc, dpw + (size_t)i * 1024 * 32, dpb + i * 1024, dtf);
    scan_kernel<<<256, 256, 0, stream>>>(dtf, xcf, dbc, xzb,
                                         Alog + (size_t)i * 1024 * 16, Dp + i * 1024, xcb);
    gemm_bt<128, 128, 2, 2, 0><<<dim3(32, 4), 256, 0, stream>>>(
        xcb, opwb + (size_t)i * 512 * 1024, h, nullptr, nullptr, 4096, 512, 1024);
  }

  resid_rms_kernel<<<TOK, 256, 0, stream>>>(h, resid, nfw, hn, 0);
  gemm_bt<128, 128, 2, 2, 2><<<dim3(32, 2), 256, 0, stream>>>(
      hn, sow1b, nullptr, t1s, sob1, 4096, 256, 512);
  gemm_bt<128, 128, 2, 2, 3><<<dim3(32, 1), 256, 0, stream>>>(
      t1s, sow2b, (float*)d_out, nullptr, sob2, 4096, 128, 256);
  gemm_bt<128, 128, 2, 2, 2><<<dim3(32, 2), 256, 0, stream>>>(
      hn, row1b, nullptr, t1r, rob1, 4096, 256, 512);
  reward_head_kernel<<<TOK / 4, 256, 0, stream>>>(
      t1r, row2, rob2, (float*)d_out + (size_t)TOK * 128);
}

// Round 2
// 1656.537 us; speedup vs baseline: 2.5315x; 2.5315x over previous
//
#include <hip/hip_runtime.h>
#include <stdint.h>

typedef unsigned short u16;
typedef __attribute__((ext_vector_type(8))) short bf16x8;
typedef __attribute__((ext_vector_type(4))) float f32x4;

static __device__ __forceinline__ u16 f2b(float f) {
  uint32_t u = __builtin_bit_cast(uint32_t, f);
  u += 0x7fffu + ((u >> 16) & 1u);
  return (u16)(u >> 16);
}
static __device__ __forceinline__ float b2f(u16 h) {
  uint32_t u = ((uint32_t)h) << 16;
  return __builtin_bit_cast(float, u);
}

// ---------------- generic f32 -> bf16 convert ----------------
__global__ void f2b_kernel(const float* __restrict__ in, u16* __restrict__ out, int n) {
  int i = blockIdx.x * 256 + threadIdx.x;
  if (i < n) out[i] = f2b(in[i]);
}

// ---------------- embedding + PE + LayerNorm ----------------
__global__ __launch_bounds__(256) void embed_ln_kernel(
    const float* __restrict__ x, const float* __restrict__ rtg,
    const float* __restrict__ Wse, const float* __restrict__ bse,
    const float* __restrict__ Wre, const float* __restrict__ bre,
    const float* __restrict__ lnw, const float* __restrict__ lnb,
    float* __restrict__ h) {
  const int tok = blockIdx.x;           // b*1024 + l
  const int l = tok & 1023;
  const int d = threadIdx.x;            // 0..255
  __shared__ float xs[128];
  __shared__ float rs[4], rq[4];
  if (d < 128) xs[d] = x[(size_t)tok * 128 + d];
  __syncthreads();
  const float* wrow = Wse + (size_t)d * 128;
  float se = bse[d];
#pragma unroll
  for (int j = 0; j < 128; j += 4) {
    float4 w4 = *(const float4*)(wrow + j);
    se += xs[j] * w4.x + xs[j + 1] * w4.y + xs[j + 2] * w4.z + xs[j + 3] * w4.w;
  }
  float re = bre[d] + rtg[tok] * Wre[d];
  // positional encoding: PE[l,dd]; dd even: sin(l*div), odd: cos(l*div), div=exp(-(2*(dd>>1))*ln(1e4)/512)
  const float c = -9.210340371976184f / 512.f;
  float div0 = expf((float)(2 * (d >> 1)) * c);
  float pe0 = (d & 1) ? cosf((float)l * div0) : sinf((float)l * div0);
  int d2 = d + 256;
  float div1 = expf((float)(2 * (d2 >> 1)) * c);
  float pe1 = (d2 & 1) ? cosf((float)l * div1) : sinf((float)l * div1);
  float h0 = se + pe0, h1 = re + pe1;
  float s = h0 + h1, q = h0 * h0 + h1 * h1;
#pragma unroll
  for (int o = 32; o; o >>= 1) { s += __shfl_xor(s, o); q += __shfl_xor(q, o); }
  if ((d & 63) == 0) { rs[d >> 6] = s; rq[d >> 6] = q; }
  __syncthreads();
  float S = rs[0] + rs[1] + rs[2] + rs[3];
  float Q = rq[0] + rq[1] + rq[2] + rq[3];
  float mean = S * (1.f / 512.f);
  float var = Q * (1.f / 512.f) - mean * mean;
  float rstd = rsqrtf(var + 1e-5f);
  size_t base = (size_t)tok * 512;
  h[base + d]  = (h0 - mean) * rstd * lnw[d]  + lnb[d];
  h[base + d2] = (h1 - mean) * rstd * lnw[d2] + lnb[d2];
}

// ---------------- residual add + RMSNorm -> bf16 ----------------
__global__ __launch_bounds__(256) void resid_rms_kernel(
    const float* __restrict__ hin, float* __restrict__ residual,
    const float* __restrict__ w, u16* __restrict__ outb, int first) {
  const int tok = blockIdx.x;
  const int t = threadIdx.x;
  __shared__ float rq[4];
  size_t base = (size_t)tok * 512;
  float v0 = hin[base + t], v1 = hin[base + t + 256];
  if (!first) { v0 += residual[base + t]; v1 += residual[base + t + 256]; }
  residual[base + t] = v0;
  residual[base + t + 256] = v1;
  float q = v0 * v0 + v1 * v1;
#pragma unroll
  for (int o = 32; o; o >>= 1) q += __shfl_xor(q, o);
  if ((t & 63) == 0) rq[t >> 6] = q;
  __syncthreads();
  float Q = rq[0] + rq[1] + rq[2] + rq[3];
  float scale = rsqrtf(Q * (1.f / 512.f) + 1e-5f);
  outb[base + t]       = f2b(v0 * scale * w[t]);
  outb[base + t + 256] = f2b(v1 * scale * w[t + 256]);
}

// ---------------- MFMA GEMM: C[M,N] = A[M,K] * Bw[N,K]^T ----------------
// A, Bw bf16 row-major. EPI: 0=f32 store, 1=bf16 store, 2=bias+relu->bf16, 3=bias->f32
template <int BM, int BN, int WM, int WN, int EPI>
__global__ __launch_bounds__(256) void gemm_bt(
    const u16* __restrict__ A, const u16* __restrict__ Bw,
    float* __restrict__ Cf, u16* __restrict__ Cb,
    const float* __restrict__ bias, int M, int N, int K) {
  constexpr int MF = BM / (WM * 16);
  constexpr int NF = BN / (WN * 16);
  constexpr int NCA = (BM * 4) / 256;   // 16B chunks per thread for A tile (BMx32 bf16)
  constexpr int NCB = (BN * 4) / 256;
  __shared__ __align__(16) u16 lA[BM * 32];
  __shared__ __align__(16) u16 lB[BN * 32];
  const int tid = threadIdx.x;
  const int lane = tid & 63;
  const int wv = tid >> 6;
  const int wr = wv / WN, wc = wv % WN;
  const int m0 = blockIdx.x * BM, n0 = blockIdx.y * BN;

  f32x4 acc[MF][NF];
#pragma unroll
  for (int i = 0; i < MF; ++i)
#pragma unroll
    for (int j = 0; j < NF; ++j) acc[i][j] = (f32x4){0.f, 0.f, 0.f, 0.f};

  const int srow = tid >> 2, sck = tid & 3;  // staging: 4 chunks of 8 bf16 per 32-wide row
  const u16* Ag = A + (size_t)(m0 + srow) * K + sck * 8;
  const u16* Bg = Bw + (size_t)(n0 + srow) * K + sck * 8;

  for (int k0 = 0; k0 < K; k0 += 32) {
    uint4 ra[NCA], rb[NCB];
#pragma unroll
    for (int it = 0; it < NCA; ++it)
      ra[it] = *(const uint4*)(Ag + (size_t)it * 64 * K + k0);
#pragma unroll
    for (int it = 0; it < NCB; ++it)
      rb[it] = *(const uint4*)(Bg + (size_t)it * 64 * K + k0);
    __syncthreads();
#pragma unroll
    for (int it = 0; it < NCA; ++it)
      *(uint4*)(&lA[(it * 256 + tid) * 8]) = ra[it];
#pragma unroll
    for (int it = 0; it < NCB; ++it)
      *(uint4*)(&lB[(it * 256 + tid) * 8]) = rb[it];
    __syncthreads();
    bf16x8 af[MF], bfr[NF];
    const int koff = (lane >> 4) * 8;
#pragma unroll
    for (int mi = 0; mi < MF; ++mi) {
      int r = wr * (MF * 16) + mi * 16 + (lane & 15);
      af[mi] = *(const bf16x8*)(&lA[r * 32 + koff]);
    }
#pragma unroll
    for (int ni = 0; ni < NF; ++ni) {
      int r = wc * (NF * 16) + ni * 16 + (lane & 15);
      bfr[ni] = *(const bf16x8*)(&lB[r * 32 + koff]);
    }
#pragma unroll
    for (int mi = 0; mi < MF; ++mi)
#pragma unroll
      for (int ni = 0; ni < NF; ++ni)
        acc[mi][ni] = __builtin_amdgcn_mfma_f32_16x16x32_bf16(af[mi], bfr[ni], acc[mi][ni], 0, 0, 0);
  }

  const int rbase = (lane >> 4) * 4;
  const int cbase = lane & 15;
#pragma unroll
  for (int mi = 0; mi < MF; ++mi) {
#pragma unroll
    for (int ni = 0; ni < NF; ++ni) {
      int row = m0 + wr * (MF * 16) + mi * 16 + rbase;
      int col = n0 + wc * (NF * 16) + ni * 16 + cbase;
      float bv = (EPI >= 2) ? bias[col] : 0.f;
#pragma unroll
      for (int r = 0; r < 4; ++r) {
        float v = acc[mi][ni][r] + bv;
        if (EPI == 2) v = fmaxf(v, 0.f);
        size_t idx = (size_t)(row + r) * N + col;
        if (EPI == 1 || EPI == 2) Cb[idx] = f2b(v);
        else Cf[idx] = v;
      }
    }
  }
}

// ---------------- causal depthwise conv(K=4) + silu ----------------
__global__ __launch_bounds__(256) void conv_silu_kernel(
    const u16* __restrict__ xz, const float* __restrict__ cw,
    const float* __restrict__ cb, float* __restrict__ xc, u16* __restrict__ xcb) {
  int idx = blockIdx.x * 256 + threadIdx.x;   // (b,t,d) over 4*1024*1024
  int d = idx & 1023;
  int t = (idx >> 10) & 1023;
  int token = idx >> 10;
  float4 w4 = *(const float4*)(cw + (size_t)d * 4);
  const float wk[4] = {w4.x, w4.y, w4.z, w4.w};
  float s = cb[d];
  const u16* xx = xz + (size_t)(token - t) * 2048 + d;  // seq start for this b, xx part (col<1024)
#pragma unroll
  for (int k = 0; k < 4; ++k) {
    int tt = t - 3 + k;
    if (tt >= 0) s += wk[k] * b2f(xx[(size_t)tt * 2048]);
  }
  float sl = s / (1.f + expf(-s));
  xc[idx] = sl;
  xcb[idx] = f2b(sl);
}

// ---------------- dt = softplus(dbc[:, :32] @ dpw^T + dpb) ----------------
__global__ __launch_bounds__(256) void dt_kernel(
    const float* __restrict__ dbc, const float* __restrict__ dpw,
    const float* __restrict__ dpb, float* __restrict__ dtout) {
  const int tok = blockIdx.x;
  const int th = threadIdx.x;
  __shared__ float s[32];
  if (th < 32) s[th] = dbc[(size_t)tok * 64 + th];
  __syncthreads();
#pragma unroll
  for (int q = 0; q < 4; ++q) {
    int dd = th + q * 256;
    const float* wr = dpw + (size_t)dd * 32;
    float a = dpb[dd];
#pragma unroll
    for (int j = 0; j < 32; j += 4) {
      float4 w4 = *(const float4*)(wr + j);
      a += s[j] * w4.x + s[j + 1] * w4.y + s[j + 2] * w4.z + s[j + 3] * w4.w;
    }
    float sp = (a > 20.f) ? a : logf(1.f + expf(a));
    dtout[(size_t)tok * 1024 + dd] = sp;
  }
}

// ---------------- chunked selective scan ----------------
// Linear recurrence h[t] = e[t]*h[t-1] + u[t] decomposes per chunk:
// h_end = E*h_start + U, E = prod(e), U = local scan from 0. NC=16 chunks of 64.
// lane layout: n = lane&15 (state), dl = lane>>4 -> d = dblk*16 + wv*4 + dl.
#define NC 16
#define TC 64

__global__ __launch_bounds__(256) void scan_part1(
    const float* __restrict__ dt, const float* __restrict__ xc,
    const float* __restrict__ dbc, const float* __restrict__ Alog,
    float* __restrict__ Ebuf, float* __restrict__ Ubuf) {
  const int blk = blockIdx.x;        // 4096 = b(4) * dblk(64) * c(16)
  const int c = blk & (NC - 1);
  const int dblk = (blk >> 4) & 63;
  const int b = blk >> 10;
  const int lane = threadIdx.x & 63;
  const int wv = threadIdx.x >> 6;
  const int n = lane & 15;
  const int dl = lane >> 4;
  const int d = dblk * 16 + wv * 4 + dl;
  const float A2 = -expf(Alog[(size_t)d * 16 + n]) * 1.4426950408889634f;
  float E = 1.f, hc = 0.f;
  size_t tok = (size_t)b * 1024 + c * TC;
  for (int t = 0; t < TC; ++t, ++tok) {
    float dtv = dt[tok * 1024 + d];
    float xcv = xc[tok * 1024 + d];
    float Bn = dbc[tok * 64 + 32 + n];
    float e = exp2f(dtv * A2);
    hc = e * hc + (dtv * xcv) * Bn;
    E *= e;
  }
  size_t o = (((size_t)b * 1024 + d) * NC + c) * 16 + n;
  Ebuf[o] = E;
  Ubuf[o] = hc;
}

__global__ __launch_bounds__(256) void scan_part2(
    const float* __restrict__ dt, const float* __restrict__ xc,
    const float* __restrict__ dbc, const u16* __restrict__ xz,
    const float* __restrict__ Alog, const float* __restrict__ Dp,
    const float* __restrict__ Ebuf, const float* __restrict__ Ubuf,
    u16* __restrict__ yg) {
  const int blk = blockIdx.x;
  const int c = blk & (NC - 1);
  const int dblk = (blk >> 4) & 63;
  const int b = blk >> 10;
  const int lane = threadIdx.x & 63;
  const int wv = threadIdx.x >> 6;
  const int n = lane & 15;
  const int dl = lane >> 4;
  const int d = dblk * 16 + wv * 4 + dl;
  const float A2 = -expf(Alog[(size_t)d * 16 + n]) * 1.4426950408889634f;
  const float Dd = Dp[d];
  // prefix over preceding chunks: h_start = scan of (E,U) pairs
  float hc = 0.f;
  size_t base = ((size_t)b * 1024 + d) * NC;
  for (int cc = 0; cc < c; ++cc) {
    size_t o = (base + cc) * 16 + n;
    hc = Ebuf[o] * hc + Ubuf[o];
  }
  size_t tok = (size_t)b * 1024 + c * TC;
  for (int t = 0; t < TC; ++t, ++tok) {
    float dtv = dt[tok * 1024 + d];
    float xcv = xc[tok * 1024 + d];
    float Bn = dbc[tok * 64 + 32 + n];
    float Cn = dbc[tok * 64 + 48 + n];
    float e = exp2f(dtv * A2);
    hc = e * hc + (dtv * xcv) * Bn;
    float y = hc * Cn;
    y += __shfl_xor(y, 1);
    y += __shfl_xor(y, 2);
    y += __shfl_xor(y, 4);
    y += __shfl_xor(y, 8);
    if (n == 0) {
      float z = b2f(xz[tok * 2048 + 1024 + d]);
      float g = z / (1.f + expf(-z));
      yg[tok * 1024 + d] = f2b((y + Dd * xcv) * g);
    }
  }
}

// ---------------- reward head: out = t1r @ ro_w2^T + b (N=1) ----------------
__global__ __launch_bounds__(256) void reward_head_kernel(
    const u16* __restrict__ t1r, const float* __restrict__ w2,
    const float* __restrict__ b2, float* __restrict__ outr) {
  int tok = blockIdx.x * 4 + (threadIdx.x >> 6);
  int lane = threadIdx.x & 63;
  float s = 0.f;
#pragma unroll
  for (int j = 0; j < 256; j += 64) s += b2f(t1r[(size_t)tok * 256 + j + lane]) * w2[j + lane];
#pragma unroll
  for (int o = 32; o; o >>= 1) s += __shfl_xor(s, o);
  if (lane == 0) outr[tok] = s + b2[0];
}

extern "C" void kernel_launch(void* const* d_in, const int* in_sizes, int n_in,
                              void* d_out, int out_size, void* d_ws, size_t ws_size,
                              hipStream_t stream) {
  const float* x    = (const float*)d_in[0];
  const float* rtg  = (const float*)d_in[1];
  const float* Wse  = (const float*)d_in[2];
  const float* bse  = (const float*)d_in[3];
  const float* Wre  = (const float*)d_in[4];
  const float* bre  = (const float*)d_in[5];
  const float* lnw  = (const float*)d_in[6];
  const float* lnb  = (const float*)d_in[7];
  const float* ipw  = (const float*)d_in[8];
  const float* cw   = (const float*)d_in[9];
  const float* cb   = (const float*)d_in[10];
  const float* xpw  = (const float*)d_in[11];
  const float* dpw  = (const float*)d_in[12];
  const float* dpb  = (const float*)d_in[13];
  const float* Alog = (const float*)d_in[14];
  const float* Dp   = (const float*)d_in[15];
  const float* opw  = (const float*)d_in[16];
  const float* nw   = (const float*)d_in[17];
  const float* nfw  = (const float*)d_in[18];
  const float* sow1 = (const float*)d_in[19];
  const float* sob1 = (const float*)d_in[20];
  const float* sow2 = (const float*)d_in[21];
  const float* sob2 = (const float*)d_in[22];
  const float* row1 = (const float*)d_in[23];
  const float* rob1 = (const float*)d_in[24];
  const float* row2 = (const float*)d_in[25];
  const float* rob2 = (const float*)d_in[26];
  (void)in_sizes; (void)n_in; (void)out_size; (void)ws_size;

  char* wsp = (char*)d_ws;
  size_t off = 0;
  auto alloc = [&](size_t bytes) -> void* {
    off = (off + 255) & ~(size_t)255;
    void* p = wsp + off;
    off += bytes;
    return p;
  };
  const int TOK = 4096;
  float* h     = (float*)alloc((size_t)TOK * 512 * 4);
  float* resid = (float*)alloc((size_t)TOK * 512 * 4);
  u16* hn      = (u16*)alloc((size_t)TOK * 512 * 2);
  u16* xzb     = (u16*)alloc((size_t)TOK * 2048 * 2);
  float* xcf   = (float*)alloc((size_t)TOK * 1024 * 4);
  u16* xcb     = (u16*)alloc((size_t)TOK * 1024 * 2);   // also reused as gated-y bf16
  float* dbc   = (float*)alloc((size_t)TOK * 64 * 4);
  float* dtf   = (float*)alloc((size_t)TOK * 1024 * 4);
  u16* ipwb    = (u16*)alloc((size_t)4 * 2048 * 512 * 2);
  u16* xpwb    = (u16*)alloc((size_t)4 * 64 * 1024 * 2);
  u16* opwb    = (u16*)alloc((size_t)4 * 512 * 1024 * 2);
  u16* sow1b   = (u16*)alloc((size_t)256 * 512 * 2);
  u16* sow2b   = (u16*)alloc((size_t)128 * 256 * 2);
  u16* row1b   = (u16*)alloc((size_t)256 * 512 * 2);
  // E/U (scan chunk state, 8MB, live during layers) aliased with
  // t1s/t1r (head temporaries, 4MB, live only after layers).
  char* shared8 = (char*)alloc((size_t)2 * 4096 * NC * 16 * 4);
  float* Ebuf  = (float*)shared8;
  float* Ubuf  = Ebuf + (size_t)4096 * NC * 16;
  u16* t1s     = (u16*)shared8;
  u16* t1r     = t1s + (size_t)TOK * 256;

  auto cvt = [&](const float* src, u16* dst, int n) {
    f2b_kernel<<<(n + 255) / 256, 256, 0, stream>>>(src, dst, n);
  };
  cvt(ipw, ipwb, 4 * 2048 * 512);
  cvt(xpw, xpwb, 4 * 64 * 1024);
  cvt(opw, opwb, 4 * 512 * 1024);
  cvt(sow1, sow1b, 256 * 512);
  cvt(sow2, sow2b, 128 * 256);
  cvt(row1, row1b, 256 * 512);

  embed_ln_kernel<<<TOK, 256, 0, stream>>>(x, rtg, Wse, bse, Wre, bre, lnw, lnb, h);

  for (int i = 0; i < 4; ++i) {
    resid_rms_kernel<<<TOK, 256, 0, stream>>>(h, resid, nw + i * 512, hn, i == 0);
    gemm_bt<128, 128, 2, 2, 1><<<dim3(32, 16), 256, 0, stream>>>(
        hn, ipwb + (size_t)i * 2048 * 512, nullptr, xzb, nullptr, 4096, 2048, 512);
    conv_silu_kernel<<<TOK * 1024 / 256, 256, 0, stream>>>(
        xzb, cw + (size_t)i * 4096, cb + i * 1024, xcf, xcb);
    gemm_bt<128, 64, 2, 2, 0><<<dim3(32, 1), 256, 0, stream>>>(
        xcb, xpwb + (size_t)i * 64 * 1024, dbc, nullptr, nullptr, 4096, 64, 1024);
    dt_kernel<<<TOK, 256, 0, stream>>>(dbc, dpw + (size_t)i * 1024 * 32, dpb + i * 1024, dtf);
    scan_part1<<<4096, 256, 0, stream>>>(dtf, xcf, dbc,
                                         Alog + (size_t)i * 1024 * 16, Ebuf, Ubuf);
    scan_part2<<<4096, 256, 0, stream>>>(dtf, xcf, dbc, xzb,
                                         Alog + (size_t)i * 1024 * 16, Dp + i * 1024,
                                         Ebuf, Ubuf, xcb);
    gemm_bt<128, 128, 2, 2, 0><<<dim3(32, 4), 256, 0, stream>>>(
        xcb, opwb + (size_t)i * 512 * 1024, h, nullptr, nullptr, 4096, 512, 1024);
  }

  resid_rms_kernel<<<TOK, 256, 0, stream>>>(h, resid, nfw, hn, 0);
  gemm_bt<128, 128, 2, 2, 2><<<dim3(32, 2), 256, 0, stream>>>(
      hn, sow1b, nullptr, t1s, sob1, 4096, 256, 512);
  gemm_bt<128, 128, 2, 2, 3><<<dim3(32, 1), 256, 0, stream>>>(
      t1s, sow2b, (float*)d_out, nullptr, sob2, 4096, 128, 256);
  gemm_bt<128, 128, 2, 2, 2><<<dim3(32, 2), 256, 0, stream>>>(
      hn, row1b, nullptr, t1r, rob1, 4096, 256, 512);
  reward_head_kernel<<<TOK / 4, 256, 0, stream>>>(
      t1r, row2, rob2, (float*)d_out + (size_t)TOK * 128);
}

// Round 3
// 1431.569 us; speedup vs baseline: 2.9293x; 1.1571x over previous
//
#include <hip/hip_runtime.h>
#include <stdint.h>

typedef unsigned short u16;
typedef __attribute__((ext_vector_type(8))) short bf16x8;
typedef __attribute__((ext_vector_type(4))) float f32x4;

static __device__ __forceinline__ u16 f2b(float f) {
  uint32_t u = __builtin_bit_cast(uint32_t, f);
  u += 0x7fffu + ((u >> 16) & 1u);
  return (u16)(u >> 16);
}
static __device__ __forceinline__ float b2f(u16 h) {
  uint32_t u = ((uint32_t)h) << 16;
  return __builtin_bit_cast(float, u);
}

// ---------------- generic f32 -> bf16 convert ----------------
__global__ void f2b_kernel(const float* __restrict__ in, u16* __restrict__ out, int n) {
  int i = blockIdx.x * 256 + threadIdx.x;
  if (i < n) out[i] = f2b(in[i]);
}

// ---------------- embedding + PE + LayerNorm ----------------
__global__ __launch_bounds__(256) void embed_ln_kernel(
    const float* __restrict__ x, const float* __restrict__ rtg,
    const float* __restrict__ Wse, const float* __restrict__ bse,
    const float* __restrict__ Wre, const float* __restrict__ bre,
    const float* __restrict__ lnw, const float* __restrict__ lnb,
    float* __restrict__ h) {
  const int tok = blockIdx.x;           // b*1024 + l
  const int l = tok & 1023;
  const int d = threadIdx.x;            // 0..255
  __shared__ float xs[128];
  __shared__ float rs[4], rq[4];
  if (d < 128) xs[d] = x[(size_t)tok * 128 + d];
  __syncthreads();
  const float* wrow = Wse + (size_t)d * 128;
  float se = bse[d];
#pragma unroll
  for (int j = 0; j < 128; j += 4) {
    float4 w4 = *(const float4*)(wrow + j);
    se += xs[j] * w4.x + xs[j + 1] * w4.y + xs[j + 2] * w4.z + xs[j + 3] * w4.w;
  }
  float re = bre[d] + rtg[tok] * Wre[d];
  const float c = -9.210340371976184f / 512.f;
  float div0 = expf((float)(2 * (d >> 1)) * c);
  float pe0 = (d & 1) ? cosf((float)l * div0) : sinf((float)l * div0);
  int d2 = d + 256;
  float div1 = expf((float)(2 * (d2 >> 1)) * c);
  float pe1 = (d2 & 1) ? cosf((float)l * div1) : sinf((float)l * div1);
  float h0 = se + pe0, h1 = re + pe1;
  float s = h0 + h1, q = h0 * h0 + h1 * h1;
#pragma unroll
  for (int o = 32; o; o >>= 1) { s += __shfl_xor(s, o); q += __shfl_xor(q, o); }
  if ((d & 63) == 0) { rs[d >> 6] = s; rq[d >> 6] = q; }
  __syncthreads();
  float S = rs[0] + rs[1] + rs[2] + rs[3];
  float Q = rq[0] + rq[1] + rq[2] + rq[3];
  float mean = S * (1.f / 512.f);
  float var = Q * (1.f / 512.f) - mean * mean;
  float rstd = rsqrtf(var + 1e-5f);
  size_t base = (size_t)tok * 512;
  h[base + d]  = (h0 - mean) * rstd * lnw[d]  + lnb[d];
  h[base + d2] = (h1 - mean) * rstd * lnw[d2] + lnb[d2];
}

// ---------------- residual add + RMSNorm -> bf16 ----------------
__global__ __launch_bounds__(256) void resid_rms_kernel(
    const float* __restrict__ hin, float* __restrict__ residual,
    const float* __restrict__ w, u16* __restrict__ outb, int first) {
  const int tok = blockIdx.x;
  const int t = threadIdx.x;
  __shared__ float rq[4];
  size_t base = (size_t)tok * 512;
  float v0 = hin[base + t], v1 = hin[base + t + 256];
  if (!first) { v0 += residual[base + t]; v1 += residual[base + t + 256]; }
  residual[base + t] = v0;
  residual[base + t + 256] = v1;
  float q = v0 * v0 + v1 * v1;
#pragma unroll
  for (int o = 32; o; o >>= 1) q += __shfl_xor(q, o);
  if ((t & 63) == 0) rq[t >> 6] = q;
  __syncthreads();
  float Q = rq[0] + rq[1] + rq[2] + rq[3];
  float scale = rsqrtf(Q * (1.f / 512.f) + 1e-5f);
  outb[base + t]       = f2b(v0 * scale * w[t]);
  outb[base + t + 256] = f2b(v1 * scale * w[t + 256]);
}

// ---------------- MFMA GEMM: C[M,N] = A[M,K] * Bw[N,K]^T ----------------
template <int BM, int BN, int WM, int WN, int EPI>
__global__ __launch_bounds__(256) void gemm_bt(
    const u16* __restrict__ A, const u16* __restrict__ Bw,
    float* __restrict__ Cf, u16* __restrict__ Cb,
    const float* __restrict__ bias, int M, int N, int K) {
  constexpr int MF = BM / (WM * 16);
  constexpr int NF = BN / (WN * 16);
  constexpr int NCA = (BM * 4) / 256;
  constexpr int NCB = (BN * 4) / 256;
  __shared__ __align__(16) u16 lA[BM * 32];
  __shared__ __align__(16) u16 lB[BN * 32];
  const int tid = threadIdx.x;
  const int lane = tid & 63;
  const int wv = tid >> 6;
  const int wr = wv / WN, wc = wv % WN;
  const int m0 = blockIdx.x * BM, n0 = blockIdx.y * BN;

  f32x4 acc[MF][NF];
#pragma unroll
  for (int i = 0; i < MF; ++i)
#pragma unroll
    for (int j = 0; j < NF; ++j) acc[i][j] = (f32x4){0.f, 0.f, 0.f, 0.f};

  const int srow = tid >> 2, sck = tid & 3;
  const u16* Ag = A + (size_t)(m0 + srow) * K + sck * 8;
  const u16* Bg = Bw + (size_t)(n0 + srow) * K + sck * 8;

  for (int k0 = 0; k0 < K; k0 += 32) {
    uint4 ra[NCA], rb[NCB];
#pragma unroll
    for (int it = 0; it < NCA; ++it)
      ra[it] = *(const uint4*)(Ag + (size_t)it * 64 * K + k0);
#pragma unroll
    for (int it = 0; it < NCB; ++it)
      rb[it] = *(const uint4*)(Bg + (size_t)it * 64 * K + k0);
    __syncthreads();
#pragma unroll
    for (int it = 0; it < NCA; ++it)
      *(uint4*)(&lA[(it * 256 + tid) * 8]) = ra[it];
#pragma unroll
    for (int it = 0; it < NCB; ++it)
      *(uint4*)(&lB[(it * 256 + tid) * 8]) = rb[it];
    __syncthreads();
    bf16x8 af[MF], bfr[NF];
    const int koff = (lane >> 4) * 8;
#pragma unroll
    for (int mi = 0; mi < MF; ++mi) {
      int r = wr * (MF * 16) + mi * 16 + (lane & 15);
      af[mi] = *(const bf16x8*)(&lA[r * 32 + koff]);
    }
#pragma unroll
    for (int ni = 0; ni < NF; ++ni) {
      int r = wc * (NF * 16) + ni * 16 + (lane & 15);
      bfr[ni] = *(const bf16x8*)(&lB[r * 32 + koff]);
    }
#pragma unroll
    for (int mi = 0; mi < MF; ++mi)
#pragma unroll
      for (int ni = 0; ni < NF; ++ni)
        acc[mi][ni] = __builtin_amdgcn_mfma_f32_16x16x32_bf16(af[mi], bfr[ni], acc[mi][ni], 0, 0, 0);
  }

  const int rbase = (lane >> 4) * 4;
  const int cbase = lane & 15;
#pragma unroll
  for (int mi = 0; mi < MF; ++mi) {
#pragma unroll
    for (int ni = 0; ni < NF; ++ni) {
      int row = m0 + wr * (MF * 16) + mi * 16 + rbase;
      int col = n0 + wc * (NF * 16) + ni * 16 + cbase;
      float bv = (EPI >= 2) ? bias[col] : 0.f;
#pragma unroll
      for (int r = 0; r < 4; ++r) {
        float v = acc[mi][ni][r] + bv;
        if (EPI == 2) v = fmaxf(v, 0.f);
        size_t idx = (size_t)(row + r) * N + col;
        if (EPI == 1 || EPI == 2) Cb[idx] = f2b(v);
        else Cf[idx] = v;
      }
    }
  }
}

// ---------------- causal depthwise conv(K=4) + silu ----------------
__global__ __launch_bounds__(256) void conv_silu_kernel(
    const u16* __restrict__ xz, const float* __restrict__ cw,
    const float* __restrict__ cb, float* __restrict__ xc, u16* __restrict__ xcb) {
  int idx = blockIdx.x * 256 + threadIdx.x;
  int d = idx & 1023;
  int t = (idx >> 10) & 1023;
  int token = idx >> 10;
  float4 w4 = *(const float4*)(cw + (size_t)d * 4);
  const float wk[4] = {w4.x, w4.y, w4.z, w4.w};
  float s = cb[d];
  const u16* xx = xz + (size_t)(token - t) * 2048 + d;
#pragma unroll
  for (int k = 0; k < 4; ++k) {
    int tt = t - 3 + k;
    if (tt >= 0) s += wk[k] * b2f(xx[(size_t)tt * 2048]);
  }
  float sl = s / (1.f + expf(-s));
  xc[idx] = sl;
  xcb[idx] = f2b(sl);
}

// ---------------- dt = softplus(dbc[:, :32] @ dpw^T + dpb) ----------------
__global__ __launch_bounds__(256) void dt_kernel(
    const float* __restrict__ dbc, const float* __restrict__ dpw,
    const float* __restrict__ dpb, float* __restrict__ dtout) {
  const int tok = blockIdx.x;
  const int th = threadIdx.x;
  __shared__ float s[32];
  if (th < 32) s[th] = dbc[(size_t)tok * 64 + th];
  __syncthreads();
#pragma unroll
  for (int q = 0; q < 4; ++q) {
    int dd = th + q * 256;
    const float* wr = dpw + (size_t)dd * 32;
    float a = dpb[dd];
#pragma unroll
    for (int j = 0; j < 32; j += 4) {
      float4 w4 = *(const float4*)(wr + j);
      a += s[j] * w4.x + s[j + 1] * w4.y + s[j + 2] * w4.z + s[j + 3] * w4.w;
    }
    float sp = (a > 20.f) ? a : logf(1.f + expf(a));
    dtout[(size_t)tok * 1024 + dd] = sp;
  }
}

// ---------------- chunked selective scan, lane-owns-d ----------------
// Each thread owns one channel d and keeps all 16 states in registers.
// B/C for the chunk staged in LDS (broadcast reads). E folded to
// exp2(A2[n]*sum_dt). Layout Ebuf/Ubuf: [b][c][d][n], n contiguous.
__global__ __launch_bounds__(256) void scan1(
    const float* __restrict__ dt, const float* __restrict__ xc,
    const float* __restrict__ dbc, const float* __restrict__ Alog,
    float* __restrict__ Ebuf, float* __restrict__ Ubuf, int NCc, int TCc) {
  const int d = blockIdx.x * 256 + threadIdx.x;
  const int c = blockIdx.y;
  const int b = blockIdx.z;
  const int t0 = c * TCc;
  __shared__ __align__(16) float sB[64][16];
  for (int i = threadIdx.x; i < TCc * 16; i += 256) {
    int t = i >> 4, n = i & 15;
    sB[t][n] = dbc[((size_t)(b * 1024 + t0 + t)) * 64 + 32 + n];
  }
  float A2[16];
#pragma unroll
  for (int q = 0; q < 4; ++q) {
    float4 a4 = *(const float4*)(Alog + (size_t)d * 16 + q * 4);
    A2[q * 4 + 0] = -expf(a4.x) * 1.4426950408889634f;
    A2[q * 4 + 1] = -expf(a4.y) * 1.4426950408889634f;
    A2[q * 4 + 2] = -expf(a4.z) * 1.4426950408889634f;
    A2[q * 4 + 3] = -expf(a4.w) * 1.4426950408889634f;
  }
  __syncthreads();
  float hc[16];
#pragma unroll
  for (int n = 0; n < 16; ++n) hc[n] = 0.f;
  float sumdt = 0.f;
  size_t tok = (size_t)b * 1024 + t0;
  for (int t = 0; t < TCc; ++t, ++tok) {
    float dtv = dt[tok * 1024 + d];
    float xcv = xc[tok * 1024 + d];
    float du = dtv * xcv;
    sumdt += dtv;
#pragma unroll
    for (int q = 0; q < 4; ++q) {
      float4 B4 = *(const float4*)(&sB[t][q * 4]);
      float e0 = exp2f(dtv * A2[q * 4 + 0]);
      float e1 = exp2f(dtv * A2[q * 4 + 1]);
      float e2 = exp2f(dtv * A2[q * 4 + 2]);
      float e3 = exp2f(dtv * A2[q * 4 + 3]);
      hc[q * 4 + 0] = e0 * hc[q * 4 + 0] + du * B4.x;
      hc[q * 4 + 1] = e1 * hc[q * 4 + 1] + du * B4.y;
      hc[q * 4 + 2] = e2 * hc[q * 4 + 2] + du * B4.z;
      hc[q * 4 + 3] = e3 * hc[q * 4 + 3] + du * B4.w;
    }
  }
  size_t o = (((size_t)b * NCc + c) * 1024 + d) * 16;
#pragma unroll
  for (int q = 0; q < 4; ++q) {
    float4 E4, U4;
    E4.x = exp2f(A2[q * 4 + 0] * sumdt); U4.x = hc[q * 4 + 0];
    E4.y = exp2f(A2[q * 4 + 1] * sumdt); U4.y = hc[q * 4 + 1];
    E4.z = exp2f(A2[q * 4 + 2] * sumdt); U4.z = hc[q * 4 + 2];
    E4.w = exp2f(A2[q * 4 + 3] * sumdt); U4.w = hc[q * 4 + 3];
    *(float4*)(Ebuf + o + q * 4) = E4;
    *(float4*)(Ubuf + o + q * 4) = U4;
  }
}

__global__ __launch_bounds__(256) void scan2(
    const float* __restrict__ dt, const float* __restrict__ xc,
    const float* __restrict__ dbc, const u16* __restrict__ xz,
    const float* __restrict__ Alog, const float* __restrict__ Dp,
    const float* __restrict__ Ebuf, const float* __restrict__ Ubuf,
    u16* __restrict__ yg, int NCc, int TCc) {
  const int d = blockIdx.x * 256 + threadIdx.x;
  const int c = blockIdx.y;
  const int b = blockIdx.z;
  const int t0 = c * TCc;
  __shared__ __align__(16) float sB[64][16];
  __shared__ __align__(16) float sC[64][16];
  for (int i = threadIdx.x; i < TCc * 16; i += 256) {
    int t = i >> 4, n = i & 15;
    size_t o = ((size_t)(b * 1024 + t0 + t)) * 64 + 32;
    sB[t][n] = dbc[o + n];
    sC[t][n] = dbc[o + 16 + n];
  }
  float A2[16];
#pragma unroll
  for (int q = 0; q < 4; ++q) {
    float4 a4 = *(const float4*)(Alog + (size_t)d * 16 + q * 4);
    A2[q * 4 + 0] = -expf(a4.x) * 1.4426950408889634f;
    A2[q * 4 + 1] = -expf(a4.y) * 1.4426950408889634f;
    A2[q * 4 + 2] = -expf(a4.z) * 1.4426950408889634f;
    A2[q * 4 + 3] = -expf(a4.w) * 1.4426950408889634f;
  }
  const float Dd = Dp[d];
  float hc[16];
#pragma unroll
  for (int n = 0; n < 16; ++n) hc[n] = 0.f;
  // prefix over preceding chunks
  for (int cc = 0; cc < c; ++cc) {
    size_t o = (((size_t)b * NCc + cc) * 1024 + d) * 16;
#pragma unroll
    for (int q = 0; q < 4; ++q) {
      float4 E4 = *(const float4*)(Ebuf + o + q * 4);
      float4 U4 = *(const float4*)(Ubuf + o + q * 4);
      hc[q * 4 + 0] = E4.x * hc[q * 4 + 0] + U4.x;
      hc[q * 4 + 1] = E4.y * hc[q * 4 + 1] + U4.y;
      hc[q * 4 + 2] = E4.z * hc[q * 4 + 2] + U4.z;
      hc[q * 4 + 3] = E4.w * hc[q * 4 + 3] + U4.w;
    }
  }
  __syncthreads();
  size_t tok = (size_t)b * 1024 + t0;
  for (int t = 0; t < TCc; ++t, ++tok) {
    float dtv = dt[tok * 1024 + d];
    float xcv = xc[tok * 1024 + d];
    float du = dtv * xcv;
    float y0 = 0.f, y1 = 0.f, y2 = 0.f, y3 = 0.f;
#pragma unroll
    for (int q = 0; q < 4; ++q) {
      float4 B4 = *(const float4*)(&sB[t][q * 4]);
      float4 C4 = *(const float4*)(&sC[t][q * 4]);
      float e0 = exp2f(dtv * A2[q * 4 + 0]);
      float e1 = exp2f(dtv * A2[q * 4 + 1]);
      float e2 = exp2f(dtv * A2[q * 4 + 2]);
      float e3 = exp2f(dtv * A2[q * 4 + 3]);
      hc[q * 4 + 0] = e0 * hc[q * 4 + 0] + du * B4.x;
      hc[q * 4 + 1] = e1 * hc[q * 4 + 1] + du * B4.y;
      hc[q * 4 + 2] = e2 * hc[q * 4 + 2] + du * B4.z;
      hc[q * 4 + 3] = e3 * hc[q * 4 + 3] + du * B4.w;
      y0 += hc[q * 4 + 0] * C4.x;
      y1 += hc[q * 4 + 1] * C4.y;
      y2 += hc[q * 4 + 2] * C4.z;
      y3 += hc[q * 4 + 3] * C4.w;
    }
    float y = (y0 + y1) + (y2 + y3);
    float z = b2f(xz[tok * 2048 + 1024 + d]);
    float g = z / (1.f + expf(-z));
    yg[tok * 1024 + d] = f2b((y + Dd * xcv) * g);
  }
}

// ---------------- reward head: out = t1r @ ro_w2^T + b (N=1) ----------------
__global__ __launch_bounds__(256) void reward_head_kernel(
    const u16* __restrict__ t1r, const float* __restrict__ w2,
    const float* __restrict__ b2, float* __restrict__ outr) {
  int tok = blockIdx.x * 4 + (threadIdx.x >> 6);
  int lane = threadIdx.x & 63;
  float s = 0.f;
#pragma unroll
  for (int j = 0; j < 256; j += 64) s += b2f(t1r[(size_t)tok * 256 + j + lane]) * w2[j + lane];
#pragma unroll
  for (int o = 32; o; o >>= 1) s += __shfl_xor(s, o);
  if (lane == 0) outr[tok] = s + b2[0];
}

extern "C" void kernel_launch(void* const* d_in, const int* in_sizes, int n_in,
                              void* d_out, int out_size, void* d_ws, size_t ws_size,
                              hipStream_t stream) {
  const float* x    = (const float*)d_in[0];
  const float* rtg  = (const float*)d_in[1];
  const float* Wse  = (const float*)d_in[2];
  const float* bse  = (const float*)d_in[3];
  const float* Wre  = (const float*)d_in[4];
  const float* bre  = (const float*)d_in[5];
  const float* lnw  = (const float*)d_in[6];
  const float* lnb  = (const float*)d_in[7];
  const float* ipw  = (const float*)d_in[8];
  const float* cw   = (const float*)d_in[9];
  const float* cb   = (const float*)d_in[10];
  const float* xpw  = (const float*)d_in[11];
  const float* dpw  = (const float*)d_in[12];
  const float* dpb  = (const float*)d_in[13];
  const float* Alog = (const float*)d_in[14];
  const float* Dp   = (const float*)d_in[15];
  const float* opw  = (const float*)d_in[16];
  const float* nw   = (const float*)d_in[17];
  const float* nfw  = (const float*)d_in[18];
  const float* sow1 = (const float*)d_in[19];
  const float* sob1 = (const float*)d_in[20];
  const float* sow2 = (const float*)d_in[21];
  const float* sob2 = (const float*)d_in[22];
  const float* row1 = (const float*)d_in[23];
  const float* rob1 = (const float*)d_in[24];
  const float* row2 = (const float*)d_in[25];
  const float* rob2 = (const float*)d_in[26];
  (void)in_sizes; (void)n_in; (void)out_size;

  char* wsp = (char*)d_ws;
  size_t off = 0;
  auto alloc = [&](size_t bytes) -> void* {
    off = (off + 255) & ~(size_t)255;
    void* p = wsp + off;
    off += bytes;
    return p;
  };
  const int TOK = 4096;
  float* h     = (float*)alloc((size_t)TOK * 512 * 4);
  float* resid = (float*)alloc((size_t)TOK * 512 * 4);
  u16* hn      = (u16*)alloc((size_t)TOK * 512 * 2);
  u16* xzb     = (u16*)alloc((size_t)TOK * 2048 * 2);
  float* xcf   = (float*)alloc((size_t)TOK * 1024 * 4);
  u16* xcb     = (u16*)alloc((size_t)TOK * 1024 * 2);
  float* dbc   = (float*)alloc((size_t)TOK * 64 * 4);
  float* dtf   = (float*)alloc((size_t)TOK * 1024 * 4);
  u16* ipwb    = (u16*)alloc((size_t)4 * 2048 * 512 * 2);
  u16* xpwb    = (u16*)alloc((size_t)4 * 64 * 1024 * 2);
  u16* opwb    = (u16*)alloc((size_t)4 * 512 * 1024 * 2);
  u16* sow1b   = (u16*)alloc((size_t)256 * 512 * 2);
  u16* sow2b   = (u16*)alloc((size_t)128 * 256 * 2);
  u16* row1b   = (u16*)alloc((size_t)256 * 512 * 2);

  // pick NC by available workspace (deterministic in ws_size -> graph-safe)
  size_t base_off = (off + 255) & ~(size_t)255;
  int NCc = (ws_size >= base_off + (size_t)2 * 4096 * 32 * 16 * 4 + 4096) ? 32 : 16;
  int TCc = 1024 / NCc;
  // E/U (scan chunk state) aliased with t1s/t1r (head temporaries).
  char* shared8 = (char*)alloc((size_t)2 * 4096 * NCc * 16 * 4);
  float* Ebuf  = (float*)shared8;
  float* Ubuf  = Ebuf + (size_t)4096 * NCc * 16;
  u16* t1s     = (u16*)shared8;
  u16* t1r     = t1s + (size_t)TOK * 256;

  auto cvt = [&](const float* src, u16* dst, int n) {
    f2b_kernel<<<(n + 255) / 256, 256, 0, stream>>>(src, dst, n);
  };
  cvt(ipw, ipwb, 4 * 2048 * 512);
  cvt(xpw, xpwb, 4 * 64 * 1024);
  cvt(opw, opwb, 4 * 512 * 1024);
  cvt(sow1, sow1b, 256 * 512);
  cvt(sow2, sow2b, 128 * 256);
  cvt(row1, row1b, 256 * 512);

  embed_ln_kernel<<<TOK, 256, 0, stream>>>(x, rtg, Wse, bse, Wre, bre, lnw, lnb, h);

  for (int i = 0; i < 4; ++i) {
    resid_rms_kernel<<<TOK, 256, 0, stream>>>(h, resid, nw + i * 512, hn, i == 0);
    gemm_bt<128, 128, 2, 2, 1><<<dim3(32, 16), 256, 0, stream>>>(
        hn, ipwb + (size_t)i * 2048 * 512, nullptr, xzb, nullptr, 4096, 2048, 512);
    conv_silu_kernel<<<TOK * 1024 / 256, 256, 0, stream>>>(
        xzb, cw + (size_t)i * 4096, cb + i * 1024, xcf, xcb);
    gemm_bt<128, 64, 2, 2, 0><<<dim3(32, 1), 256, 0, stream>>>(
        xcb, xpwb + (size_t)i * 64 * 1024, dbc, nullptr, nullptr, 4096, 64, 1024);
    dt_kernel<<<TOK, 256, 0, stream>>>(dbc, dpw + (size_t)i * 1024 * 32, dpb + i * 1024, dtf);
    scan1<<<dim3(4, NCc - 1, 4), 256, 0, stream>>>(
        dtf, xcf, dbc, Alog + (size_t)i * 1024 * 16, Ebuf, Ubuf, NCc, TCc);
    scan2<<<dim3(4, NCc, 4), 256, 0, stream>>>(
        dtf, xcf, dbc, xzb, Alog + (size_t)i * 1024 * 16, Dp + i * 1024,
        Ebuf, Ubuf, xcb, NCc, TCc);
    gemm_bt<128, 128, 2, 2, 0><<<dim3(32, 4), 256, 0, stream>>>(
        xcb, opwb + (size_t)i * 512 * 1024, h, nullptr, nullptr, 4096, 512, 1024);
  }

  resid_rms_kernel<<<TOK, 256, 0, stream>>>(h, resid, nfw, hn, 0);
  gemm_bt<128, 128, 2, 2, 2><<<dim3(32, 2), 256, 0, stream>>>(
      hn, sow1b, nullptr, t1s, sob1, 4096, 256, 512);
  gemm_bt<128, 128, 2, 2, 3><<<dim3(32, 1), 256, 0, stream>>>(
      t1s, sow2b, (float*)d_out, nullptr, sob2, 4096, 128, 256);
  gemm_bt<128, 128, 2, 2, 2><<<dim3(32, 2), 256, 0, stream>>>(
      hn, row1b, nullptr, t1r, rob1, 4096, 256, 512);
  reward_head_kernel<<<TOK / 4, 256, 0, stream>>>(
      t1r, row2, rob2, (float*)d_out + (size_t)TOK * 128);
}

// Round 4
// 947.806 us; speedup vs baseline: 4.4245x; 1.5104x over previous
//
#include <hip/hip_runtime.h>
#include <stdint.h>

typedef unsigned short u16;
typedef __attribute__((ext_vector_type(8))) short bf16x8;
typedef __attribute__((ext_vector_type(4))) float f32x4;

static __device__ __forceinline__ u16 f2b(float f) {
  uint32_t u = __builtin_bit_cast(uint32_t, f);
  u += 0x7fffu + ((u >> 16) & 1u);
  return (u16)(u >> 16);
}
static __device__ __forceinline__ float b2f(u16 h) {
  uint32_t u = ((uint32_t)h) << 16;
  return __builtin_bit_cast(float, u);
}

#define GLDS16(gsrc, ldst)                                                        \
  __builtin_amdgcn_global_load_lds(                                               \
      (const __attribute__((address_space(1))) void*)(gsrc),                      \
      (__attribute__((address_space(3))) void*)(ldst), 16, 0, 0)

// ---------------- generic f32 -> bf16 convert ----------------
__global__ void f2b_kernel(const float* __restrict__ in, u16* __restrict__ out, int n) {
  int i = blockIdx.x * 256 + threadIdx.x;
  if (i < n) out[i] = f2b(in[i]);
}

// ---------------- PE table: PE[l][dd] ----------------
__global__ __launch_bounds__(256) void pe_kernel(float* __restrict__ PEt) {
  const int l = blockIdx.x;
  const float c = -9.210340371976184f / 512.f;
#pragma unroll
  for (int q = 0; q < 2; ++q) {
    int dd = threadIdx.x + q * 256;
    float div = expf((float)(2 * (dd >> 1)) * c);
    float v = (dd & 1) ? cosf((float)l * div) : sinf((float)l * div);
    PEt[(size_t)l * 512 + dd] = v;
  }
}

// ---------------- embedding + PE + LayerNorm (16 tokens/block) ----------------
__global__ __launch_bounds__(256) void embed_ln2(
    const float* __restrict__ x, const float* __restrict__ rtg,
    const float* __restrict__ Wse, const float* __restrict__ bse,
    const float* __restrict__ Wre, const float* __restrict__ bre,
    const float* __restrict__ lnw, const float* __restrict__ lnb,
    const float* __restrict__ PEt, float* __restrict__ h) {
  const int tid = threadIdx.x;
  const int tok0 = blockIdx.x * 16;
  const int l0 = tok0 & 1023;
  __shared__ float xs[16][128];
  __shared__ float rt[16];
  __shared__ float sw[16][2][4];
  for (int i = tid; i < 16 * 128; i += 256) ((float*)xs)[i] = x[(size_t)tok0 * 128 + i];
  if (tid < 16) rt[tid] = rtg[tok0 + tid];
  __syncthreads();
  const int d = tid;
  float acc[16];
#pragma unroll
  for (int tt = 0; tt < 16; ++tt) acc[tt] = 0.f;
  const float* wrow = Wse + (size_t)d * 128;
  for (int k0 = 0; k0 < 128; k0 += 8) {
    float4 wa = *(const float4*)(wrow + k0);
    float4 wb = *(const float4*)(wrow + k0 + 4);
#pragma unroll
    for (int tt = 0; tt < 16; ++tt) {
      const float* xr = &xs[tt][k0];
      acc[tt] += xr[0] * wa.x + xr[1] * wa.y + xr[2] * wa.z + xr[3] * wa.w +
                 xr[4] * wb.x + xr[5] * wb.y + xr[6] * wb.z + xr[7] * wb.w;
    }
  }
  const float seb = bse[d], reW = Wre[d], reB = bre[d];
  const int lane = tid & 63, wv = tid >> 6;
  float h1a[16];
#pragma unroll
  for (int tt = 0; tt < 16; ++tt) {
    float h0 = acc[tt] + seb + PEt[(size_t)(l0 + tt) * 512 + d];
    float h1 = reB + rt[tt] * reW + PEt[(size_t)(l0 + tt) * 512 + 256 + d];
    acc[tt] = h0;
    h1a[tt] = h1;
    float s = h0 + h1, q = h0 * h0 + h1 * h1;
#pragma unroll
    for (int o = 32; o; o >>= 1) { s += __shfl_xor(s, o); q += __shfl_xor(q, o); }
    if (lane == 0) { sw[tt][0][wv] = s; sw[tt][1][wv] = q; }
  }
  __syncthreads();
#pragma unroll
  for (int tt = 0; tt < 16; ++tt) {
    float S = sw[tt][0][0] + sw[tt][0][1] + sw[tt][0][2] + sw[tt][0][3];
    float Q = sw[tt][1][0] + sw[tt][1][1] + sw[tt][1][2] + sw[tt][1][3];
    float mean = S * (1.f / 512.f);
    float var = Q * (1.f / 512.f) - mean * mean;
    float rstd = rsqrtf(var + 1e-5f);
    size_t base = (size_t)(tok0 + tt) * 512;
    h[base + d]       = (acc[tt] - mean) * rstd * lnw[d] + lnb[d];
    h[base + 256 + d] = (h1a[tt] - mean) * rstd * lnw[256 + d] + lnb[256 + d];
  }
}

// ---------------- residual add + RMSNorm -> bf16 ----------------
__global__ __launch_bounds__(256) void resid_rms_kernel(
    const float* __restrict__ hin, float* __restrict__ residual,
    const float* __restrict__ w, u16* __restrict__ outb, int first) {
  const int tok = blockIdx.x;
  const int t = threadIdx.x;
  __shared__ float rq[4];
  size_t base = (size_t)tok * 512;
  float v0 = hin[base + t], v1 = hin[base + t + 256];
  if (!first) { v0 += residual[base + t]; v1 += residual[base + t + 256]; }
  residual[base + t] = v0;
  residual[base + t + 256] = v1;
  float q = v0 * v0 + v1 * v1;
#pragma unroll
  for (int o = 32; o; o >>= 1) q += __shfl_xor(q, o);
  if ((t & 63) == 0) rq[t >> 6] = q;
  __syncthreads();
  float Q = rq[0] + rq[1] + rq[2] + rq[3];
  float scale = rsqrtf(Q * (1.f / 512.f) + 1e-5f);
  outb[base + t]       = f2b(v0 * scale * w[t]);
  outb[base + t + 256] = f2b(v1 * scale * w[t + 256]);
}

// ---------------- MFMA GEMM: C[M,N] = A[M,K] * Bw[N,K]^T ----------------
// global_load_lds (width 16) staging; optional K-split via blockIdx.z
// (partials written to Cf + z*M*N). EPI: 0=f32, 1=bf16, 2=bias+relu->bf16, 3=bias->f32
template <int BM, int BN, int WM, int WN, int EPI>
__global__ __launch_bounds__(256) void gemm_bt(
    const u16* __restrict__ A, const u16* __restrict__ Bw,
    float* __restrict__ Cf, u16* __restrict__ Cb,
    const float* __restrict__ bias, int M, int N, int K) {
  constexpr int MF = BM / (WM * 16);
  constexpr int NF = BN / (WN * 16);
  constexpr int NCA = (BM * 4) / 256;
  constexpr int NCB = (BN * 4) / 256;
  __shared__ __align__(16) u16 lA[BM * 32];
  __shared__ __align__(16) u16 lB[BN * 32];
  const int tid = threadIdx.x;
  const int lane = tid & 63;
  const int wv = tid >> 6;
  const int wr = wv / WN, wc = wv % WN;
  const int m0 = blockIdx.x * BM, n0 = blockIdx.y * BN;
  const int kchunk = K / gridDim.z;
  const int kb = blockIdx.z * kchunk;

  f32x4 acc[MF][NF];
#pragma unroll
  for (int i = 0; i < MF; ++i)
#pragma unroll
    for (int j = 0; j < NF; ++j) acc[i][j] = (f32x4){0.f, 0.f, 0.f, 0.f};

  const int srow = tid >> 2, sck = tid & 3;
  const u16* Ag = A + (size_t)(m0 + srow) * K + sck * 8 + kb;
  const u16* Bg = Bw + (size_t)(n0 + srow) * K + sck * 8 + kb;

  for (int k0 = 0; k0 < kchunk; k0 += 32) {
#pragma unroll
    for (int it = 0; it < NCA; ++it)
      GLDS16(Ag + (size_t)it * 64 * K + k0, &lA[(it * 256 + tid) * 8]);
#pragma unroll
    for (int it = 0; it < NCB; ++it)
      GLDS16(Bg + (size_t)it * 64 * K + k0, &lB[(it * 256 + tid) * 8]);
    __syncthreads();
    bf16x8 af[MF], bfr[NF];
    const int koff = (lane >> 4) * 8;
#pragma unroll
    for (int mi = 0; mi < MF; ++mi) {
      int r = wr * (MF * 16) + mi * 16 + (lane & 15);
      af[mi] = *(const bf16x8*)(&lA[r * 32 + koff]);
    }
#pragma unroll
    for (int ni = 0; ni < NF; ++ni) {
      int r = wc * (NF * 16) + ni * 16 + (lane & 15);
      bfr[ni] = *(const bf16x8*)(&lB[r * 32 + koff]);
    }
#pragma unroll
    for (int mi = 0; mi < MF; ++mi)
#pragma unroll
      for (int ni = 0; ni < NF; ++ni)
        acc[mi][ni] = __builtin_amdgcn_mfma_f32_16x16x32_bf16(af[mi], bfr[ni], acc[mi][ni], 0, 0, 0);
    __syncthreads();
  }

  float* co = Cf + (size_t)blockIdx.z * (size_t)M * N;
  const int rbase = (lane >> 4) * 4;
  const int cbase = lane & 15;
#pragma unroll
  for (int mi = 0; mi < MF; ++mi) {
#pragma unroll
    for (int ni = 0; ni < NF; ++ni) {
      int row = m0 + wr * (MF * 16) + mi * 16 + rbase;
      int col = n0 + wc * (NF * 16) + ni * 16 + cbase;
      float bv = (EPI >= 2) ? bias[col] : 0.f;
#pragma unroll
      for (int r = 0; r < 4; ++r) {
        float v = acc[mi][ni][r] + bv;
        if (EPI == 2) v = fmaxf(v, 0.f);
        size_t idx = (size_t)(row + r) * N + col;
        if (EPI == 1 || EPI == 2) Cb[idx] = f2b(v);
        else co[idx] = v;
      }
    }
  }
}

// ---------------- causal depthwise conv(K=4) + silu ----------------
__global__ __launch_bounds__(256) void conv_silu_kernel(
    const u16* __restrict__ xz, const float* __restrict__ cw,
    const float* __restrict__ cb, float* __restrict__ xc, u16* __restrict__ xcb) {
  int idx = blockIdx.x * 256 + threadIdx.x;
  int d = idx & 1023;
  int t = (idx >> 10) & 1023;
  int token = idx >> 10;
  float4 w4 = *(const float4*)(cw + (size_t)d * 4);
  const float wk[4] = {w4.x, w4.y, w4.z, w4.w};
  float s = cb[d];
  const u16* xx = xz + (size_t)(token - t) * 2048 + d;
#pragma unroll
  for (int k = 0; k < 4; ++k) {
    int tt = t - 3 + k;
    if (tt >= 0) s += wk[k] * b2f(xx[(size_t)tt * 2048]);
  }
  float sl = s / (1.f + expf(-s));
  xc[idx] = sl;
  xcb[idx] = f2b(sl);
}

// ---------------- reduce x_proj K-split partials + dt = softplus(...) ----------------
__global__ __launch_bounds__(256) void dt_kernel(
    const float* __restrict__ P, const float* __restrict__ dpw,
    const float* __restrict__ dpb, float* __restrict__ dtout,
    float* __restrict__ dbcr) {
  const int tok = blockIdx.x;
  const int th = threadIdx.x;
  __shared__ float s[64];
  if (th < 64) {
    const size_t str = (size_t)4096 * 64;
    size_t o = (size_t)tok * 64 + th;
    float v = P[o] + P[str + o] + P[2 * str + o] + P[3 * str + o];
    s[th] = v;
    dbcr[o] = v;
  }
  __syncthreads();
#pragma unroll
  for (int q = 0; q < 4; ++q) {
    int dd = th + q * 256;
    const float* wr = dpw + (size_t)dd * 32;
    float a = dpb[dd];
#pragma unroll
    for (int j = 0; j < 32; j += 4) {
      float4 w4 = *(const float4*)(wr + j);
      a += s[j] * w4.x + s[j + 1] * w4.y + s[j + 2] * w4.z + s[j + 3] * w4.w;
    }
    float sp = (a > 20.f) ? a : logf(1.f + expf(a));
    dtout[(size_t)tok * 1024 + dd] = sp;
  }
}

// ---------------- chunked selective scan, lane-owns-d ----------------
// E/U layout: [b][c][n][d] (d innermost -> coalesced in both kernels)
__global__ __launch_bounds__(256) void scan1(
    const float* __restrict__ dt, const float* __restrict__ xc,
    const float* __restrict__ dbc, const float* __restrict__ Alog,
    float* __restrict__ Ebuf, float* __restrict__ Ubuf, int NCc, int TCc) {
  const int d = blockIdx.x * 256 + threadIdx.x;
  const int c = blockIdx.y;
  const int b = blockIdx.z;
  const int t0 = c * TCc;
  __shared__ __align__(16) float sB[64][16];
  for (int i = threadIdx.x; i < TCc * 16; i += 256) {
    int t = i >> 4, n = i & 15;
    sB[t][n] = dbc[((size_t)(b * 1024 + t0 + t)) * 64 + 32 + n];
  }
  float A2[16];
#pragma unroll
  for (int q = 0; q < 4; ++q) {
    float4 a4 = *(const float4*)(Alog + (size_t)d * 16 + q * 4);
    A2[q * 4 + 0] = -expf(a4.x) * 1.4426950408889634f;
    A2[q * 4 + 1] = -expf(a4.y) * 1.4426950408889634f;
    A2[q * 4 + 2] = -expf(a4.z) * 1.4426950408889634f;
    A2[q * 4 + 3] = -expf(a4.w) * 1.4426950408889634f;
  }
  __syncthreads();
  float hc[16];
#pragma unroll
  for (int n = 0; n < 16; ++n) hc[n] = 0.f;
  float sumdt = 0.f;
  size_t tok = (size_t)b * 1024 + t0;
  for (int t = 0; t < TCc; ++t, ++tok) {
    float dtv = dt[tok * 1024 + d];
    float xcv = xc[tok * 1024 + d];
    float du = dtv * xcv;
    sumdt += dtv;
#pragma unroll
    for (int q = 0; q < 4; ++q) {
      float4 B4 = *(const float4*)(&sB[t][q * 4]);
      float e0 = exp2f(dtv * A2[q * 4 + 0]);
      float e1 = exp2f(dtv * A2[q * 4 + 1]);
      float e2 = exp2f(dtv * A2[q * 4 + 2]);
      float e3 = exp2f(dtv * A2[q * 4 + 3]);
      hc[q * 4 + 0] = e0 * hc[q * 4 + 0] + du * B4.x;
      hc[q * 4 + 1] = e1 * hc[q * 4 + 1] + du * B4.y;
      hc[q * 4 + 2] = e2 * hc[q * 4 + 2] + du * B4.z;
      hc[q * 4 + 3] = e3 * hc[q * 4 + 3] + du * B4.w;
    }
  }
  size_t ob = (((size_t)b * NCc + c) * 16) * 1024 + d;
#pragma unroll
  for (int n = 0; n < 16; ++n) {
    Ebuf[ob + (size_t)n * 1024] = exp2f(A2[n] * sumdt);
    Ubuf[ob + (size_t)n * 1024] = hc[n];
  }
}

__global__ __launch_bounds__(256) void scan2(
    const float* __restrict__ dt, const float* __restrict__ xc,
    const float* __restrict__ dbc, const u16* __restrict__ xz,
    const float* __restrict__ Alog, const float* __restrict__ Dp,
    const float* __restrict__ Ebuf, const float* __restrict__ Ubuf,
    u16* __restrict__ yg, int NCc, int TCc) {
  const int d = blockIdx.x * 256 + threadIdx.x;
  const int c = blockIdx.y;
  const int b = blockIdx.z;
  const int t0 = c * TCc;
  __shared__ __align__(16) float sB[64][16];
  __shared__ __align__(16) float sC[64][16];
  for (int i = threadIdx.x; i < TCc * 16; i += 256) {
    int t = i >> 4, n = i & 15;
    size_t o = ((size_t)(b * 1024 + t0 + t)) * 64 + 32;
    sB[t][n] = dbc[o + n];
    sC[t][n] = dbc[o + 16 + n];
  }
  float A2[16];
#pragma unroll
  for (int q = 0; q < 4; ++q) {
    float4 a4 = *(const float4*)(Alog + (size_t)d * 16 + q * 4);
    A2[q * 4 + 0] = -expf(a4.x) * 1.4426950408889634f;
    A2[q * 4 + 1] = -expf(a4.y) * 1.4426950408889634f;
    A2[q * 4 + 2] = -expf(a4.z) * 1.4426950408889634f;
    A2[q * 4 + 3] = -expf(a4.w) * 1.4426950408889634f;
  }
  const float Dd = Dp[d];
  float hc[16];
#pragma unroll
  for (int n = 0; n < 16; ++n) hc[n] = 0.f;
  for (int cc = 0; cc < c; ++cc) {
    size_t ob = (((size_t)b * NCc + cc) * 16) * 1024 + d;
#pragma unroll
    for (int n = 0; n < 16; ++n)
      hc[n] = Ebuf[ob + (size_t)n * 1024] * hc[n] + Ubuf[ob + (size_t)n * 1024];
  }
  __syncthreads();
  size_t tok = (size_t)b * 1024 + t0;
  for (int t = 0; t < TCc; ++t, ++tok) {
    float dtv = dt[tok * 1024 + d];
    float xcv = xc[tok * 1024 + d];
    float du = dtv * xcv;
    float y0 = 0.f, y1 = 0.f, y2 = 0.f, y3 = 0.f;
#pragma unroll
    for (int q = 0; q < 4; ++q) {
      float4 B4 = *(const float4*)(&sB[t][q * 4]);
      float4 C4 = *(const float4*)(&sC[t][q * 4]);
      float e0 = exp2f(dtv * A2[q * 4 + 0]);
      float e1 = exp2f(dtv * A2[q * 4 + 1]);
      float e2 = exp2f(dtv * A2[q * 4 + 2]);
      float e3 = exp2f(dtv * A2[q * 4 + 3]);
      hc[q * 4 + 0] = e0 * hc[q * 4 + 0] + du * B4.x;
      hc[q * 4 + 1] = e1 * hc[q * 4 + 1] + du * B4.y;
      hc[q * 4 + 2] = e2 * hc[q * 4 + 2] + du * B4.z;
      hc[q * 4 + 3] = e3 * hc[q * 4 + 3] + du * B4.w;
      y0 += hc[q * 4 + 0] * C4.x;
      y1 += hc[q * 4 + 1] * C4.y;
      y2 += hc[q * 4 + 2] * C4.z;
      y3 += hc[q * 4 + 3] * C4.w;
    }
    float y = (y0 + y1) + (y2 + y3);
    float z = b2f(xz[tok * 2048 + 1024 + d]);
    float g = z / (1.f + expf(-z));
    yg[tok * 1024 + d] = f2b((y + Dd * xcv) * g);
  }
}

// ---------------- reward head: out = t1r @ ro_w2^T + b (N=1) ----------------
__global__ __launch_bounds__(256) void reward_head_kernel(
    const u16* __restrict__ t1r, const float* __restrict__ w2,
    const float* __restrict__ b2, float* __restrict__ outr) {
  int tok = blockIdx.x * 4 + (threadIdx.x >> 6);
  int lane = threadIdx.x & 63;
  float s = 0.f;
#pragma unroll
  for (int j = 0; j < 256; j += 64) s += b2f(t1r[(size_t)tok * 256 + j + lane]) * w2[j + lane];
#pragma unroll
  for (int o = 32; o; o >>= 1) s += __shfl_xor(s, o);
  if (lane == 0) outr[tok] = s + b2[0];
}

extern "C" void kernel_launch(void* const* d_in, const int* in_sizes, int n_in,
                              void* d_out, int out_size, void* d_ws, size_t ws_size,
                              hipStream_t stream) {
  const float* x    = (const float*)d_in[0];
  const float* rtg  = (const float*)d_in[1];
  const float* Wse  = (const float*)d_in[2];
  const float* bse  = (const float*)d_in[3];
  const float* Wre  = (const float*)d_in[4];
  const float* bre  = (const float*)d_in[5];
  const float* lnw  = (const float*)d_in[6];
  const float* lnb  = (const float*)d_in[7];
  const float* ipw  = (const float*)d_in[8];
  const float* cw   = (const float*)d_in[9];
  const float* cb   = (const float*)d_in[10];
  const float* xpw  = (const float*)d_in[11];
  const float* dpw  = (const float*)d_in[12];
  const float* dpb  = (const float*)d_in[13];
  const float* Alog = (const float*)d_in[14];
  const float* Dp   = (const float*)d_in[15];
  const float* opw  = (const float*)d_in[16];
  const float* nw   = (const float*)d_in[17];
  const float* nfw  = (const float*)d_in[18];
  const float* sow1 = (const float*)d_in[19];
  const float* sob1 = (const float*)d_in[20];
  const float* sow2 = (const float*)d_in[21];
  const float* sob2 = (const float*)d_in[22];
  const float* row1 = (const float*)d_in[23];
  const float* rob1 = (const float*)d_in[24];
  const float* row2 = (const float*)d_in[25];
  const float* rob2 = (const float*)d_in[26];
  (void)in_sizes; (void)n_in; (void)out_size;

  char* wsp = (char*)d_ws;
  size_t off = 0;
  auto alloc = [&](size_t bytes) -> void* {
    off = (off + 255) & ~(size_t)255;
    void* p = wsp + off;
    off += bytes;
    return p;
  };
  const int TOK = 4096;
  float* h     = (float*)alloc((size_t)TOK * 512 * 4);
  float* resid = (float*)alloc((size_t)TOK * 512 * 4);
  u16* hn      = (u16*)alloc((size_t)TOK * 512 * 2);
  u16* xzb     = (u16*)alloc((size_t)TOK * 2048 * 2);
  float* xcf   = (float*)alloc((size_t)TOK * 1024 * 4);
  u16* xcb     = (u16*)alloc((size_t)TOK * 1024 * 2);
  float* dbcP  = (float*)alloc((size_t)4 * TOK * 64 * 4);   // x_proj K-split partials
  float* dbc   = (float*)alloc((size_t)TOK * 64 * 4);       // reduced
  float* dtf   = (float*)alloc((size_t)TOK * 1024 * 4);
  float* PEt   = (float*)alloc((size_t)1024 * 512 * 4);
  u16* ipwb    = (u16*)alloc((size_t)4 * 2048 * 512 * 2);
  u16* xpwb    = (u16*)alloc((size_t)4 * 64 * 1024 * 2);
  u16* opwb    = (u16*)alloc((size_t)4 * 512 * 1024 * 2);
  u16* sow1b   = (u16*)alloc((size_t)256 * 512 * 2);
  u16* sow2b   = (u16*)alloc((size_t)128 * 256 * 2);
  u16* row1b   = (u16*)alloc((size_t)256 * 512 * 2);

  // pick NC by available workspace (deterministic in ws_size -> graph-safe)
  size_t base_off = (off + 255) & ~(size_t)255;
  int NCc = (ws_size >= base_off + (size_t)2 * 4096 * 32 * 16 * 4 + 4096) ? 32 : 16;
  int TCc = 1024 / NCc;
  // E/U (scan chunk state) aliased with t1s/t1r (head temporaries).
  char* shared8 = (char*)alloc((size_t)2 * 4096 * NCc * 16 * 4);
  float* Ebuf  = (float*)shared8;
  float* Ubuf  = Ebuf + (size_t)4096 * NCc * 16;
  u16* t1s     = (u16*)shared8;
  u16* t1r     = t1s + (size_t)TOK * 256;

  auto cvt = [&](const float* src, u16* dst, int n) {
    f2b_kernel<<<(n + 255) / 256, 256, 0, stream>>>(src, dst, n);
  };
  cvt(ipw, ipwb, 4 * 2048 * 512);
  cvt(xpw, xpwb, 4 * 64 * 1024);
  cvt(opw, opwb, 4 * 512 * 1024);
  cvt(sow1, sow1b, 256 * 512);
  cvt(sow2, sow2b, 128 * 256);
  cvt(row1, row1b, 256 * 512);

  pe_kernel<<<1024, 256, 0, stream>>>(PEt);
  embed_ln2<<<256, 256, 0, stream>>>(x, rtg, Wse, bse, Wre, bre, lnw, lnb, PEt, h);

  for (int i = 0; i < 4; ++i) {
    resid_rms_kernel<<<TOK, 256, 0, stream>>>(h, resid, nw + i * 512, hn, i == 0);
    gemm_bt<128, 128, 2, 2, 1><<<dim3(32, 16, 1), 256, 0, stream>>>(
        hn, ipwb + (size_t)i * 2048 * 512, nullptr, xzb, nullptr, 4096, 2048, 512);
    conv_silu_kernel<<<TOK * 1024 / 256, 256, 0, stream>>>(
        xzb, cw + (size_t)i * 4096, cb + i * 1024, xcf, xcb);
    gemm_bt<128, 64, 2, 2, 0><<<dim3(32, 1, 4), 256, 0, stream>>>(
        xcb, xpwb + (size_t)i * 64 * 1024, dbcP, nullptr, nullptr, 4096, 64, 1024);
    dt_kernel<<<TOK, 256, 0, stream>>>(dbcP, dpw + (size_t)i * 1024 * 32, dpb + i * 1024,
                                       dtf, dbc);
    scan1<<<dim3(4, NCc - 1, 4), 256, 0, stream>>>(
        dtf, xcf, dbc, Alog + (size_t)i * 1024 * 16, Ebuf, Ubuf, NCc, TCc);
    scan2<<<dim3(4, NCc, 4), 256, 0, stream>>>(
        dtf, xcf, dbc, xzb, Alog + (size_t)i * 1024 * 16, Dp + i * 1024,
        Ebuf, Ubuf, xcb, NCc, TCc);
    gemm_bt<128, 64, 2, 2, 0><<<dim3(32, 8, 1), 256, 0, stream>>>(
        xcb, opwb + (size_t)i * 512 * 1024, h, nullptr, nullptr, 4096, 512, 1024);
  }

  resid_rms_kernel<<<TOK, 256, 0, stream>>>(h, resid, nfw, hn, 0);
  gemm_bt<64, 64, 2, 2, 2><<<dim3(64, 4, 1), 256, 0, stream>>>(
      hn, sow1b, nullptr, t1s, sob1, 4096, 256, 512);
  gemm_bt<64, 64, 2, 2, 3><<<dim3(64, 2, 1), 256, 0, stream>>>(
      t1s, sow2b, (float*)d_out, nullptr, sob2, 4096, 128, 256);
  gemm_bt<64, 64, 2, 2, 2><<<dim3(64, 4, 1), 256, 0, stream>>>(
      hn, row1b, nullptr, t1r, rob1, 4096, 256, 512);
  reward_head_kernel<<<TOK / 4, 256, 0, stream>>>(
      t1r, row2, rob2, (float*)d_out + (size_t)TOK * 128);
}

// Round 5
// 730.667 us; speedup vs baseline: 5.7393x; 1.2972x over previous
//
#include <hip/hip_runtime.h>
#include <stdint.h>

typedef unsigned short u16;
typedef __attribute__((ext_vector_type(8))) short bf16x8;
typedef __attribute__((ext_vector_type(4))) float f32x4;

static __device__ __forceinline__ u16 f2b(float f) {
  uint32_t u = __builtin_bit_cast(uint32_t, f);
  u += 0x7fffu + ((u >> 16) & 1u);
  return (u16)(u >> 16);
}
static __device__ __forceinline__ float b2f(u16 h) {
  uint32_t u = ((uint32_t)h) << 16;
  return __builtin_bit_cast(float, u);
}

#define GLDS16(gsrc, ldst)                                                        \
  __builtin_amdgcn_global_load_lds(                                               \
      (const __attribute__((address_space(1))) void*)(gsrc),                      \
      (__attribute__((address_space(3))) void*)(ldst), 16, 0, 0)

// ---------------- generic f32 -> bf16 convert ----------------
__global__ void f2b_kernel(const float* __restrict__ in, u16* __restrict__ out, int n) {
  int i = blockIdx.x * 256 + threadIdx.x;
  if (i < n) out[i] = f2b(in[i]);
}

// ---------------- PE table: PE[l][dd] ----------------
__global__ __launch_bounds__(256) void pe_kernel(float* __restrict__ PEt) {
  const int l = blockIdx.x;
  const float c = -9.210340371976184f / 512.f;
#pragma unroll
  for (int q = 0; q < 2; ++q) {
    int dd = threadIdx.x + q * 256;
    float div = expf((float)(2 * (dd >> 1)) * c);
    float v = (dd & 1) ? cosf((float)l * div) : sinf((float)l * div);
    PEt[(size_t)l * 512 + dd] = v;
  }
}

// ---------------- dpw transpose: [4][1024][32] -> [4][32][1024] ----------------
__global__ __launch_bounds__(256) void dpw_t_kernel(const float* __restrict__ dpw,
                                                    float* __restrict__ dpwT) {
  const int l = blockIdx.y;
  int idx = blockIdx.x * 256 + threadIdx.x;   // over 32*1024 outputs
  int j = idx >> 10, dd = idx & 1023;
  dpwT[(size_t)l * 32768 + idx] = dpw[(size_t)l * 32768 + (size_t)dd * 32 + j];
}

// ---------------- embedding + PE + LayerNorm (16 tokens/block) ----------------
__global__ __launch_bounds__(256) void embed_ln2(
    const float* __restrict__ x, const float* __restrict__ rtg,
    const float* __restrict__ Wse, const float* __restrict__ bse,
    const float* __restrict__ Wre, const float* __restrict__ bre,
    const float* __restrict__ lnw, const float* __restrict__ lnb,
    const float* __restrict__ PEt, float* __restrict__ h) {
  const int tid = threadIdx.x;
  const int tok0 = blockIdx.x * 16;
  const int l0 = tok0 & 1023;
  __shared__ float xs[16][128];
  __shared__ float rt[16];
  __shared__ float sw[16][2][4];
  for (int i = tid; i < 16 * 128; i += 256) ((float*)xs)[i] = x[(size_t)tok0 * 128 + i];
  if (tid < 16) rt[tid] = rtg[tok0 + tid];
  __syncthreads();
  const int d = tid;
  float acc[16];
#pragma unroll
  for (int tt = 0; tt < 16; ++tt) acc[tt] = 0.f;
  const float* wrow = Wse + (size_t)d * 128;
  for (int k0 = 0; k0 < 128; k0 += 8) {
    float4 wa = *(const float4*)(wrow + k0);
    float4 wb = *(const float4*)(wrow + k0 + 4);
#pragma unroll
    for (int tt = 0; tt < 16; ++tt) {
      const float* xr = &xs[tt][k0];
      acc[tt] += xr[0] * wa.x + xr[1] * wa.y + xr[2] * wa.z + xr[3] * wa.w +
                 xr[4] * wb.x + xr[5] * wb.y + xr[6] * wb.z + xr[7] * wb.w;
    }
  }
  const float seb = bse[d], reW = Wre[d], reB = bre[d];
  const int lane = tid & 63, wv = tid >> 6;
  float h1a[16];
#pragma unroll
  for (int tt = 0; tt < 16; ++tt) {
    float h0 = acc[tt] + seb + PEt[(size_t)(l0 + tt) * 512 + d];
    float h1 = reB + rt[tt] * reW + PEt[(size_t)(l0 + tt) * 512 + 256 + d];
    acc[tt] = h0;
    h1a[tt] = h1;
    float s = h0 + h1, q = h0 * h0 + h1 * h1;
#pragma unroll
    for (int o = 32; o; o >>= 1) { s += __shfl_xor(s, o); q += __shfl_xor(q, o); }
    if (lane == 0) { sw[tt][0][wv] = s; sw[tt][1][wv] = q; }
  }
  __syncthreads();
#pragma unroll
  for (int tt = 0; tt < 16; ++tt) {
    float S = sw[tt][0][0] + sw[tt][0][1] + sw[tt][0][2] + sw[tt][0][3];
    float Q = sw[tt][1][0] + sw[tt][1][1] + sw[tt][1][2] + sw[tt][1][3];
    float mean = S * (1.f / 512.f);
    float var = Q * (1.f / 512.f) - mean * mean;
    float rstd = rsqrtf(var + 1e-5f);
    size_t base = (size_t)(tok0 + tt) * 512;
    h[base + d]       = (acc[tt] - mean) * rstd * lnw[d] + lnb[d];
    h[base + 256 + d] = (h1a[tt] - mean) * rstd * lnw[256 + d] + lnb[256 + d];
  }
}

// ---------------- residual add + RMSNorm -> bf16 ----------------
__global__ __launch_bounds__(256) void resid_rms_kernel(
    const float* __restrict__ hin, float* __restrict__ residual,
    const float* __restrict__ w, u16* __restrict__ outb, int first) {
  const int tok = blockIdx.x;
  const int t = threadIdx.x;
  __shared__ float rq[4];
  size_t base = (size_t)tok * 512;
  float v0 = hin[base + t], v1 = hin[base + t + 256];
  if (!first) { v0 += residual[base + t]; v1 += residual[base + t + 256]; }
  residual[base + t] = v0;
  residual[base + t + 256] = v1;
  float q = v0 * v0 + v1 * v1;
#pragma unroll
  for (int o = 32; o; o >>= 1) q += __shfl_xor(q, o);
  if ((t & 63) == 0) rq[t >> 6] = q;
  __syncthreads();
  float Q = rq[0] + rq[1] + rq[2] + rq[3];
  float scale = rsqrtf(Q * (1.f / 512.f) + 1e-5f);
  outb[base + t]       = f2b(v0 * scale * w[t]);
  outb[base + t + 256] = f2b(v1 * scale * w[t + 256]);
}

// ---------------- MFMA GEMM: C[M,N] = A[M,K] * Bw[N,K]^T ----------------
template <int BM, int BN, int WM, int WN, int EPI>
__global__ __launch_bounds__(256) void gemm_bt(
    const u16* __restrict__ A, const u16* __restrict__ Bw,
    float* __restrict__ Cf, u16* __restrict__ Cb,
    const float* __restrict__ bias, int M, int N, int K) {
  constexpr int MF = BM / (WM * 16);
  constexpr int NF = BN / (WN * 16);
  constexpr int NCA = (BM * 4) / 256;
  constexpr int NCB = (BN * 4) / 256;
  __shared__ __align__(16) u16 lA[BM * 32];
  __shared__ __align__(16) u16 lB[BN * 32];
  const int tid = threadIdx.x;
  const int lane = tid & 63;
  const int wv = tid >> 6;
  const int wr = wv / WN, wc = wv % WN;
  const int m0 = blockIdx.x * BM, n0 = blockIdx.y * BN;
  const int kchunk = K / gridDim.z;
  const int kb = blockIdx.z * kchunk;

  f32x4 acc[MF][NF];
#pragma unroll
  for (int i = 0; i < MF; ++i)
#pragma unroll
    for (int j = 0; j < NF; ++j) acc[i][j] = (f32x4){0.f, 0.f, 0.f, 0.f};

  const int srow = tid >> 2, sck = tid & 3;
  const u16* Ag = A + (size_t)(m0 + srow) * K + sck * 8 + kb;
  const u16* Bg = Bw + (size_t)(n0 + srow) * K + sck * 8 + kb;

  for (int k0 = 0; k0 < kchunk; k0 += 32) {
#pragma unroll
    for (int it = 0; it < NCA; ++it)
      GLDS16(Ag + (size_t)it * 64 * K + k0, &lA[(it * 256 + tid) * 8]);
#pragma unroll
    for (int it = 0; it < NCB; ++it)
      GLDS16(Bg + (size_t)it * 64 * K + k0, &lB[(it * 256 + tid) * 8]);
    __syncthreads();
    bf16x8 af[MF], bfr[NF];
    const int koff = (lane >> 4) * 8;
#pragma unroll
    for (int mi = 0; mi < MF; ++mi) {
      int r = wr * (MF * 16) + mi * 16 + (lane & 15);
      af[mi] = *(const bf16x8*)(&lA[r * 32 + koff]);
    }
#pragma unroll
    for (int ni = 0; ni < NF; ++ni) {
      int r = wc * (NF * 16) + ni * 16 + (lane & 15);
      bfr[ni] = *(const bf16x8*)(&lB[r * 32 + koff]);
    }
#pragma unroll
    for (int mi = 0; mi < MF; ++mi)
#pragma unroll
      for (int ni = 0; ni < NF; ++ni)
        acc[mi][ni] = __builtin_amdgcn_mfma_f32_16x16x32_bf16(af[mi], bfr[ni], acc[mi][ni], 0, 0, 0);
    __syncthreads();
  }

  float* co = Cf + (size_t)blockIdx.z * (size_t)M * N;
  const int rbase = (lane >> 4) * 4;
  const int cbase = lane & 15;
#pragma unroll
  for (int mi = 0; mi < MF; ++mi) {
#pragma unroll
    for (int ni = 0; ni < NF; ++ni) {
      int row = m0 + wr * (MF * 16) + mi * 16 + rbase;
      int col = n0 + wc * (NF * 16) + ni * 16 + cbase;
      float bv = (EPI >= 2) ? bias[col] : 0.f;
#pragma unroll
      for (int r = 0; r < 4; ++r) {
        float v = acc[mi][ni][r] + bv;
        if (EPI == 2) v = fmaxf(v, 0.f);
        size_t idx = (size_t)(row + r) * N + col;
        if (EPI == 1 || EPI == 2) Cb[idx] = f2b(v);
        else co[idx] = v;
      }
    }
  }
}

// ---------------- causal depthwise conv(K=4) + silu ----------------
__global__ __launch_bounds__(256) void conv_silu_kernel(
    const u16* __restrict__ xz, const float* __restrict__ cw,
    const float* __restrict__ cb, float* __restrict__ xc, u16* __restrict__ xcb) {
  int idx = blockIdx.x * 256 + threadIdx.x;
  int d = idx & 1023;
  int t = (idx >> 10) & 1023;
  int token = idx >> 10;
  float4 w4 = *(const float4*)(cw + (size_t)d * 4);
  const float wk[4] = {w4.x, w4.y, w4.z, w4.w};
  float s = cb[d];
  const u16* xx = xz + (size_t)(token - t) * 2048 + d;
#pragma unroll
  for (int k = 0; k < 4; ++k) {
    int tt = t - 3 + k;
    if (tt >= 0) s += wk[k] * b2f(xx[(size_t)tt * 2048]);
  }
  float sl = s / (1.f + expf(-s));
  xc[idx] = sl;
  xcb[idx] = f2b(sl);
}

// ---------------- reduce x_proj partials + dt = softplus(dbc@dpwT + dpb) ----------------
// 16 tokens/block; dpwT[j][dd] coalesced; dbc staged+reduced in LDS.
__global__ __launch_bounds__(256) void dt_kernel2(
    const float* __restrict__ P, const float* __restrict__ dpwT,
    const float* __restrict__ dpb, float* __restrict__ dtout,
    float* __restrict__ dbcr) {
  const int tid = threadIdx.x;
  const int tok0 = blockIdx.x * 16;
  __shared__ float sm[16][64];
  const size_t str = (size_t)4096 * 64;
  for (int i = tid; i < 16 * 64; i += 256) {
    size_t o = (size_t)tok0 * 64 + i;
    float v = P[o] + P[str + o] + P[2 * str + o] + P[3 * str + o];
    ((float*)sm)[i] = v;
    dbcr[o] = v;
  }
  __syncthreads();
  float acc0[16], acc1[16], acc2[16], acc3[16];
#pragma unroll
  for (int t = 0; t < 16; ++t) { acc0[t] = 0.f; acc1[t] = 0.f; acc2[t] = 0.f; acc3[t] = 0.f; }
#pragma unroll 4
  for (int j = 0; j < 32; ++j) {
    float w0 = dpwT[(size_t)j * 1024 + tid];
    float w1 = dpwT[(size_t)j * 1024 + 256 + tid];
    float w2 = dpwT[(size_t)j * 1024 + 512 + tid];
    float w3 = dpwT[(size_t)j * 1024 + 768 + tid];
#pragma unroll
    for (int t = 0; t < 16; ++t) {
      float sv = sm[t][j];
      acc0[t] += sv * w0;
      acc1[t] += sv * w1;
      acc2[t] += sv * w2;
      acc3[t] += sv * w3;
    }
  }
  const float b0 = dpb[tid], b1 = dpb[256 + tid], b2 = dpb[512 + tid], b3 = dpb[768 + tid];
#pragma unroll
  for (int t = 0; t < 16; ++t) {
    size_t o = (size_t)(tok0 + t) * 1024 + tid;
    float a0 = acc0[t] + b0, a1 = acc1[t] + b1, a2 = acc2[t] + b2, a3 = acc3[t] + b3;
    dtout[o]       = (a0 > 20.f) ? a0 : logf(1.f + expf(a0));
    dtout[o + 256] = (a1 > 20.f) ? a1 : logf(1.f + expf(a1));
    dtout[o + 512] = (a2 > 20.f) ? a2 : logf(1.f + expf(a2));
    dtout[o + 768] = (a3 > 20.f) ? a3 : logf(1.f + expf(a3));
  }
}

// ---------------- chunked selective scan, lane-owns-d ----------------
// E/U layout: [b][c][n][d] (d innermost -> coalesced in both kernels)
__global__ __launch_bounds__(256) void scan1(
    const float* __restrict__ dt, const float* __restrict__ xc,
    const float* __restrict__ dbc, const float* __restrict__ Alog,
    float* __restrict__ Ebuf, float* __restrict__ Ubuf, int NCc, int TCc) {
  const int d = blockIdx.x * 256 + threadIdx.x;
  const int c = blockIdx.y;
  const int b = blockIdx.z;
  const int t0 = c * TCc;
  __shared__ __align__(16) float sB[64][16];
  for (int i = threadIdx.x; i < TCc * 16; i += 256) {
    int t = i >> 4, n = i & 15;
    sB[t][n] = dbc[((size_t)(b * 1024 + t0 + t)) * 64 + 32 + n];
  }
  float A2[16];
#pragma unroll
  for (int q = 0; q < 4; ++q) {
    float4 a4 = *(const float4*)(Alog + (size_t)d * 16 + q * 4);
    A2[q * 4 + 0] = -expf(a4.x) * 1.4426950408889634f;
    A2[q * 4 + 1] = -expf(a4.y) * 1.4426950408889634f;
    A2[q * 4 + 2] = -expf(a4.z) * 1.4426950408889634f;
    A2[q * 4 + 3] = -expf(a4.w) * 1.4426950408889634f;
  }
  __syncthreads();
  float hc[16];
#pragma unroll
  for (int n = 0; n < 16; ++n) hc[n] = 0.f;
  float sumdt = 0.f;
  size_t tok = (size_t)b * 1024 + t0;
  for (int t = 0; t < TCc; ++t, ++tok) {
    float dtv = dt[tok * 1024 + d];
    float xcv = xc[tok * 1024 + d];
    float du = dtv * xcv;
    sumdt += dtv;
#pragma unroll
    for (int q = 0; q < 4; ++q) {
      float4 B4 = *(const float4*)(&sB[t][q * 4]);
      float e0 = exp2f(dtv * A2[q * 4 + 0]);
      float e1 = exp2f(dtv * A2[q * 4 + 1]);
      float e2 = exp2f(dtv * A2[q * 4 + 2]);
      float e3 = exp2f(dtv * A2[q * 4 + 3]);
      hc[q * 4 + 0] = e0 * hc[q * 4 + 0] + du * B4.x;
      hc[q * 4 + 1] = e1 * hc[q * 4 + 1] + du * B4.y;
      hc[q * 4 + 2] = e2 * hc[q * 4 + 2] + du * B4.z;
      hc[q * 4 + 3] = e3 * hc[q * 4 + 3] + du * B4.w;
    }
  }
  size_t ob = (((size_t)b * NCc + c) * 16) * 1024 + d;
#pragma unroll
  for (int n = 0; n < 16; ++n) {
    Ebuf[ob + (size_t)n * 1024] = exp2f(A2[n] * sumdt);
    Ubuf[ob + (size_t)n * 1024] = hc[n];
  }
}

__global__ __launch_bounds__(256) void scan2(
    const float* __restrict__ dt, const float* __restrict__ xc,
    const float* __restrict__ dbc, const u16* __restrict__ xz,
    const float* __restrict__ Alog, const float* __restrict__ Dp,
    const float* __restrict__ Ebuf, const float* __restrict__ Ubuf,
    u16* __restrict__ yg, int NCc, int TCc) {
  const int d = blockIdx.x * 256 + threadIdx.x;
  const int c = blockIdx.y;
  const int b = blockIdx.z;
  const int t0 = c * TCc;
  __shared__ __align__(16) float sB[64][16];
  __shared__ __align__(16) float sC[64][16];
  for (int i = threadIdx.x; i < TCc * 16; i += 256) {
    int t = i >> 4, n = i & 15;
    size_t o = ((size_t)(b * 1024 + t0 + t)) * 64 + 32;
    sB[t][n] = dbc[o + n];
    sC[t][n] = dbc[o + 16 + n];
  }
  float A2[16];
#pragma unroll
  for (int q = 0; q < 4; ++q) {
    float4 a4 = *(const float4*)(Alog + (size_t)d * 16 + q * 4);
    A2[q * 4 + 0] = -expf(a4.x) * 1.4426950408889634f;
    A2[q * 4 + 1] = -expf(a4.y) * 1.4426950408889634f;
    A2[q * 4 + 2] = -expf(a4.z) * 1.4426950408889634f;
    A2[q * 4 + 3] = -expf(a4.w) * 1.4426950408889634f;
  }
  const float Dd = Dp[d];
  float hc[16];
#pragma unroll
  for (int n = 0; n < 16; ++n) hc[n] = 0.f;
  for (int cc = 0; cc < c; ++cc) {
    size_t ob = (((size_t)b * NCc + cc) * 16) * 1024 + d;
#pragma unroll
    for (int n = 0; n < 16; ++n)
      hc[n] = Ebuf[ob + (size_t)n * 1024] * hc[n] + Ubuf[ob + (size_t)n * 1024];
  }
  __syncthreads();
  size_t tok = (size_t)b * 1024 + t0;
  for (int t = 0; t < TCc; ++t, ++tok) {
    float dtv = dt[tok * 1024 + d];
    float xcv = xc[tok * 1024 + d];
    float du = dtv * xcv;
    float y0 = 0.f, y1 = 0.f, y2 = 0.f, y3 = 0.f;
#pragma unroll
    for (int q = 0; q < 4; ++q) {
      float4 B4 = *(const float4*)(&sB[t][q * 4]);
      float4 C4 = *(const float4*)(&sC[t][q * 4]);
      float e0 = exp2f(dtv * A2[q * 4 + 0]);
      float e1 = exp2f(dtv * A2[q * 4 + 1]);
      float e2 = exp2f(dtv * A2[q * 4 + 2]);
      float e3 = exp2f(dtv * A2[q * 4 + 3]);
      hc[q * 4 + 0] = e0 * hc[q * 4 + 0] + du * B4.x;
      hc[q * 4 + 1] = e1 * hc[q * 4 + 1] + du * B4.y;
      hc[q * 4 + 2] = e2 * hc[q * 4 + 2] + du * B4.z;
      hc[q * 4 + 3] = e3 * hc[q * 4 + 3] + du * B4.w;
      y0 += hc[q * 4 + 0] * C4.x;
      y1 += hc[q * 4 + 1] * C4.y;
      y2 += hc[q * 4 + 2] * C4.z;
      y3 += hc[q * 4 + 3] * C4.w;
    }
    float y = (y0 + y1) + (y2 + y3);
    float z = b2f(xz[tok * 2048 + 1024 + d]);
    float g = z / (1.f + expf(-z));
    yg[tok * 1024 + d] = f2b((y + Dd * xcv) * g);
  }
}

// ---------------- reward head: out = t1r @ ro_w2^T + b (N=1) ----------------
__global__ __launch_bounds__(256) void reward_head_kernel(
    const u16* __restrict__ t1r, const float* __restrict__ w2,
    const float* __restrict__ b2, float* __restrict__ outr) {
  int tok = blockIdx.x * 4 + (threadIdx.x >> 6);
  int lane = threadIdx.x & 63;
  float s = 0.f;
#pragma unroll
  for (int j = 0; j < 256; j += 64) s += b2f(t1r[(size_t)tok * 256 + j + lane]) * w2[j + lane];
#pragma unroll
  for (int o = 32; o; o >>= 1) s += __shfl_xor(s, o);
  if (lane == 0) outr[tok] = s + b2[0];
}

extern "C" void kernel_launch(void* const* d_in, const int* in_sizes, int n_in,
                              void* d_out, int out_size, void* d_ws, size_t ws_size,
                              hipStream_t stream) {
  const float* x    = (const float*)d_in[0];
  const float* rtg  = (const float*)d_in[1];
  const float* Wse  = (const float*)d_in[2];
  const float* bse  = (const float*)d_in[3];
  const float* Wre  = (const float*)d_in[4];
  const float* bre  = (const float*)d_in[5];
  const float* lnw  = (const float*)d_in[6];
  const float* lnb  = (const float*)d_in[7];
  const float* ipw  = (const float*)d_in[8];
  const float* cw   = (const float*)d_in[9];
  const float* cb   = (const float*)d_in[10];
  const float* xpw  = (const float*)d_in[11];
  const float* dpw  = (const float*)d_in[12];
  const float* dpb  = (const float*)d_in[13];
  const float* Alog = (const float*)d_in[14];
  const float* Dp   = (const float*)d_in[15];
  const float* opw  = (const float*)d_in[16];
  const float* nw   = (const float*)d_in[17];
  const float* nfw  = (const float*)d_in[18];
  const float* sow1 = (const float*)d_in[19];
  const float* sob1 = (const float*)d_in[20];
  const float* sow2 = (const float*)d_in[21];
  const float* sob2 = (const float*)d_in[22];
  const float* row1 = (const float*)d_in[23];
  const float* rob1 = (const float*)d_in[24];
  const float* row2 = (const float*)d_in[25];
  const float* rob2 = (const float*)d_in[26];
  (void)in_sizes; (void)n_in; (void)out_size;

  char* wsp = (char*)d_ws;
  size_t off = 0;
  auto alloc = [&](size_t bytes) -> void* {
    off = (off + 255) & ~(size_t)255;
    void* p = wsp + off;
    off += bytes;
    return p;
  };
  const int TOK = 4096;
  float* h     = (float*)alloc((size_t)TOK * 512 * 4);
  float* resid = (float*)alloc((size_t)TOK * 512 * 4);
  u16* hn      = (u16*)alloc((size_t)TOK * 512 * 2);
  u16* xzb     = (u16*)alloc((size_t)TOK * 2048 * 2);
  float* xcf   = (float*)alloc((size_t)TOK * 1024 * 4);
  u16* xcb     = (u16*)alloc((size_t)TOK * 1024 * 2);
  float* dbcP  = (float*)alloc((size_t)4 * TOK * 64 * 4);   // x_proj K-split partials
  float* dbc   = (float*)alloc((size_t)TOK * 64 * 4);       // reduced
  float* dtf   = (float*)alloc((size_t)TOK * 1024 * 4);
  float* PEt   = (float*)alloc((size_t)1024 * 512 * 4);
  float* dpwT  = (float*)alloc((size_t)4 * 32 * 1024 * 4);
  u16* ipwb    = (u16*)alloc((size_t)4 * 2048 * 512 * 2);
  u16* xpwb    = (u16*)alloc((size_t)4 * 64 * 1024 * 2);
  u16* opwb    = (u16*)alloc((size_t)4 * 512 * 1024 * 2);
  u16* sow1b   = (u16*)alloc((size_t)256 * 512 * 2);
  u16* sow2b   = (u16*)alloc((size_t)128 * 256 * 2);
  u16* row1b   = (u16*)alloc((size_t)256 * 512 * 2);

  // pick NC by available workspace (deterministic in ws_size -> graph-safe)
  size_t base_off = (off + 255) & ~(size_t)255;
  int NCc = (ws_size >= base_off + (size_t)2 * 4096 * 32 * 16 * 4 + 4096) ? 32 : 16;
  int TCc = 1024 / NCc;
  // E/U (scan chunk state) aliased with t1s/t1r (head temporaries).
  char* shared8 = (char*)alloc((size_t)2 * 4096 * NCc * 16 * 4);
  float* Ebuf  = (float*)shared8;
  float* Ubuf  = Ebuf + (size_t)4096 * NCc * 16;
  u16* t1s     = (u16*)shared8;
  u16* t1r     = t1s + (size_t)TOK * 256;

  auto cvt = [&](const float* src, u16* dst, int n) {
    f2b_kernel<<<(n + 255) / 256, 256, 0, stream>>>(src, dst, n);
  };
  cvt(ipw, ipwb, 4 * 2048 * 512);
  cvt(xpw, xpwb, 4 * 64 * 1024);
  cvt(opw, opwb, 4 * 512 * 1024);
  cvt(sow1, sow1b, 256 * 512);
  cvt(sow2, sow2b, 128 * 256);
  cvt(row1, row1b, 256 * 512);

  pe_kernel<<<1024, 256, 0, stream>>>(PEt);
  dpw_t_kernel<<<dim3(128, 4), 256, 0, stream>>>(dpw, dpwT);
  embed_ln2<<<256, 256, 0, stream>>>(x, rtg, Wse, bse, Wre, bre, lnw, lnb, PEt, h);

  for (int i = 0; i < 4; ++i) {
    resid_rms_kernel<<<TOK, 256, 0, stream>>>(h, resid, nw + i * 512, hn, i == 0);
    gemm_bt<128, 128, 2, 2, 1><<<dim3(32, 16, 1), 256, 0, stream>>>(
        hn, ipwb + (size_t)i * 2048 * 512, nullptr, xzb, nullptr, 4096, 2048, 512);
    conv_silu_kernel<<<TOK * 1024 / 256, 256, 0, stream>>>(
        xzb, cw + (size_t)i * 4096, cb + i * 1024, xcf, xcb);
    gemm_bt<128, 64, 2, 2, 0><<<dim3(32, 1, 4), 256, 0, stream>>>(
        xcb, xpwb + (size_t)i * 64 * 1024, dbcP, nullptr, nullptr, 4096, 64, 1024);
    dt_kernel2<<<TOK / 16, 256, 0, stream>>>(dbcP, dpwT + (size_t)i * 32 * 1024,
                                             dpb + i * 1024, dtf, dbc);
    scan1<<<dim3(4, NCc - 1, 4), 256, 0, stream>>>(
        dtf, xcf, dbc, Alog + (size_t)i * 1024 * 16, Ebuf, Ubuf, NCc, TCc);
    scan2<<<dim3(4, NCc, 4), 256, 0, stream>>>(
        dtf, xcf, dbc, xzb, Alog + (size_t)i * 1024 * 16, Dp + i * 1024,
        Ebuf, Ubuf, xcb, NCc, TCc);
    gemm_bt<128, 64, 2, 2, 0><<<dim3(32, 8, 1), 256, 0, stream>>>(
        xcb, opwb + (size_t)i * 512 * 1024, h, nullptr, nullptr, 4096, 512, 1024);
  }

  resid_rms_kernel<<<TOK, 256, 0, stream>>>(h, resid, nfw, hn, 0);
  gemm_bt<64, 64, 2, 2, 2><<<dim3(64, 4, 1), 256, 0, stream>>>(
      hn, sow1b, nullptr, t1s, sob1, 4096, 256, 512);
  gemm_bt<64, 64, 2, 2, 3><<<dim3(64, 2, 1), 256, 0, stream>>>(
      t1s, sow2b, (float*)d_out, nullptr, sob2, 4096, 128, 256);
  gemm_bt<64, 64, 2, 2, 2><<<dim3(64, 4, 1), 256, 0, stream>>>(
      hn, row1b, nullptr, t1r, rob1, 4096, 256, 512);
  reward_head_kernel<<<TOK / 4, 256, 0, stream>>>(
      t1r, row2, rob2, (float*)d_out + (size_t)TOK * 128);
}

// Round 6
// 721.041 us; speedup vs baseline: 5.8159x; 1.0133x over previous
//
#include <hip/hip_runtime.h>
#include <stdint.h>

typedef unsigned short u16;
typedef __attribute__((ext_vector_type(8))) short bf16x8;
typedef __attribute__((ext_vector_type(4))) float f32x4;

static __device__ __forceinline__ u16 f2b(float f) {
  uint32_t u = __builtin_bit_cast(uint32_t, f);
  u += 0x7fffu + ((u >> 16) & 1u);
  return (u16)(u >> 16);
}
static __device__ __forceinline__ float b2f(u16 h) {
  uint32_t u = ((uint32_t)h) << 16;
  return __builtin_bit_cast(float, u);
}

#define GLDS16(gsrc, ldst)                                                        \
  __builtin_amdgcn_global_load_lds(                                               \
      (const __attribute__((address_space(1))) void*)(gsrc),                      \
      (__attribute__((address_space(3))) void*)(ldst), 16, 0, 0)

// ---------------- generic f32 -> bf16 convert ----------------
__global__ void f2b_kernel(const float* __restrict__ in, u16* __restrict__ out, int n) {
  int i = blockIdx.x * 256 + threadIdx.x;
  if (i < n) out[i] = f2b(in[i]);
}

// ---------------- PE table: PE[l][dd] ----------------
__global__ __launch_bounds__(256) void pe_kernel(float* __restrict__ PEt) {
  const int l = blockIdx.x;
  const float c = -9.210340371976184f / 512.f;
#pragma unroll
  for (int q = 0; q < 2; ++q) {
    int dd = threadIdx.x + q * 256;
    float div = expf((float)(2 * (dd >> 1)) * c);
    float v = (dd & 1) ? cosf((float)l * div) : sinf((float)l * div);
    PEt[(size_t)l * 512 + dd] = v;
  }
}

// ---------------- dpw transpose: [4][1024][32] -> [4][32][1024] ----------------
__global__ __launch_bounds__(256) void dpw_t_kernel(const float* __restrict__ dpw,
                                                    float* __restrict__ dpwT) {
  const int l = blockIdx.y;
  int idx = blockIdx.x * 256 + threadIdx.x;   // over 32*1024 outputs
  int j = idx >> 10, dd = idx & 1023;
  dpwT[(size_t)l * 32768 + idx] = dpw[(size_t)l * 32768 + (size_t)dd * 32 + j];
}

// ---------------- embedding + PE + LayerNorm (16 tokens/block) ----------------
__global__ __launch_bounds__(256) void embed_ln2(
    const float* __restrict__ x, const float* __restrict__ rtg,
    const float* __restrict__ Wse, const float* __restrict__ bse,
    const float* __restrict__ Wre, const float* __restrict__ bre,
    const float* __restrict__ lnw, const float* __restrict__ lnb,
    const float* __restrict__ PEt, float* __restrict__ h) {
  const int tid = threadIdx.x;
  const int tok0 = blockIdx.x * 16;
  const int l0 = tok0 & 1023;
  __shared__ float xs[16][128];
  __shared__ float rt[16];
  __shared__ float sw[16][2][4];
  for (int i = tid; i < 16 * 128; i += 256) ((float*)xs)[i] = x[(size_t)tok0 * 128 + i];
  if (tid < 16) rt[tid] = rtg[tok0 + tid];
  __syncthreads();
  const int d = tid;
  float acc[16];
#pragma unroll
  for (int tt = 0; tt < 16; ++tt) acc[tt] = 0.f;
  const float* wrow = Wse + (size_t)d * 128;
  for (int k0 = 0; k0 < 128; k0 += 8) {
    float4 wa = *(const float4*)(wrow + k0);
    float4 wb = *(const float4*)(wrow + k0 + 4);
#pragma unroll
    for (int tt = 0; tt < 16; ++tt) {
      const float* xr = &xs[tt][k0];
      acc[tt] += xr[0] * wa.x + xr[1] * wa.y + xr[2] * wa.z + xr[3] * wa.w +
                 xr[4] * wb.x + xr[5] * wb.y + xr[6] * wb.z + xr[7] * wb.w;
    }
  }
  const float seb = bse[d], reW = Wre[d], reB = bre[d];
  const int lane = tid & 63, wv = tid >> 6;
  float h1a[16];
#pragma unroll
  for (int tt = 0; tt < 16; ++tt) {
    float h0 = acc[tt] + seb + PEt[(size_t)(l0 + tt) * 512 + d];
    float h1 = reB + rt[tt] * reW + PEt[(size_t)(l0 + tt) * 512 + 256 + d];
    acc[tt] = h0;
    h1a[tt] = h1;
    float s = h0 + h1, q = h0 * h0 + h1 * h1;
#pragma unroll
    for (int o = 32; o; o >>= 1) { s += __shfl_xor(s, o); q += __shfl_xor(q, o); }
    if (lane == 0) { sw[tt][0][wv] = s; sw[tt][1][wv] = q; }
  }
  __syncthreads();
#pragma unroll
  for (int tt = 0; tt < 16; ++tt) {
    float S = sw[tt][0][0] + sw[tt][0][1] + sw[tt][0][2] + sw[tt][0][3];
    float Q = sw[tt][1][0] + sw[tt][1][1] + sw[tt][1][2] + sw[tt][1][3];
    float mean = S * (1.f / 512.f);
    float var = Q * (1.f / 512.f) - mean * mean;
    float rstd = rsqrtf(var + 1e-5f);
    size_t base = (size_t)(tok0 + tt) * 512;
    h[base + d]       = (acc[tt] - mean) * rstd * lnw[d] + lnb[d];
    h[base + 256 + d] = (h1a[tt] - mean) * rstd * lnw[256 + d] + lnb[256 + d];
  }
}

// ---------------- residual add + RMSNorm -> bf16 ----------------
__global__ __launch_bounds__(256) void resid_rms_kernel(
    const float* __restrict__ hin, float* __restrict__ residual,
    const float* __restrict__ w, u16* __restrict__ outb, int first) {
  const int tok = blockIdx.x;
  const int t = threadIdx.x;
  __shared__ float rq[4];
  size_t base = (size_t)tok * 512;
  float v0 = hin[base + t], v1 = hin[base + t + 256];
  if (!first) { v0 += residual[base + t]; v1 += residual[base + t + 256]; }
  residual[base + t] = v0;
  residual[base + t + 256] = v1;
  float q = v0 * v0 + v1 * v1;
#pragma unroll
  for (int o = 32; o; o >>= 1) q += __shfl_xor(q, o);
  if ((t & 63) == 0) rq[t >> 6] = q;
  __syncthreads();
  float Q = rq[0] + rq[1] + rq[2] + rq[3];
  float scale = rsqrtf(Q * (1.f / 512.f) + 1e-5f);
  outb[base + t]       = f2b(v0 * scale * w[t]);
  outb[base + t + 256] = f2b(v1 * scale * w[t + 256]);
}

// ---------------- MFMA GEMM: C[M,N] = A[M,K] * Bw[N,K]^T ----------------
template <int BM, int BN, int WM, int WN, int EPI>
__global__ __launch_bounds__(256) void gemm_bt(
    const u16* __restrict__ A, const u16* __restrict__ Bw,
    float* __restrict__ Cf, u16* __restrict__ Cb,
    const float* __restrict__ bias, int M, int N, int K) {
  constexpr int MF = BM / (WM * 16);
  constexpr int NF = BN / (WN * 16);
  constexpr int NCA = (BM * 4) / 256;
  constexpr int NCB = (BN * 4) / 256;
  __shared__ __align__(16) u16 lA[BM * 32];
  __shared__ __align__(16) u16 lB[BN * 32];
  const int tid = threadIdx.x;
  const int lane = tid & 63;
  const int wv = tid >> 6;
  const int wr = wv / WN, wc = wv % WN;
  const int m0 = blockIdx.x * BM, n0 = blockIdx.y * BN;
  const int kchunk = K / gridDim.z;
  const int kb = blockIdx.z * kchunk;

  f32x4 acc[MF][NF];
#pragma unroll
  for (int i = 0; i < MF; ++i)
#pragma unroll
    for (int j = 0; j < NF; ++j) acc[i][j] = (f32x4){0.f, 0.f, 0.f, 0.f};

  const int srow = tid >> 2, sck = tid & 3;
  const u16* Ag = A + (size_t)(m0 + srow) * K + sck * 8 + kb;
  const u16* Bg = Bw + (size_t)(n0 + srow) * K + sck * 8 + kb;

  for (int k0 = 0; k0 < kchunk; k0 += 32) {
#pragma unroll
    for (int it = 0; it < NCA; ++it)
      GLDS16(Ag + (size_t)it * 64 * K + k0, &lA[(it * 256 + tid) * 8]);
#pragma unroll
    for (int it = 0; it < NCB; ++it)
      GLDS16(Bg + (size_t)it * 64 * K + k0, &lB[(it * 256 + tid) * 8]);
    __syncthreads();
    bf16x8 af[MF], bfr[NF];
    const int koff = (lane >> 4) * 8;
#pragma unroll
    for (int mi = 0; mi < MF; ++mi) {
      int r = wr * (MF * 16) + mi * 16 + (lane & 15);
      af[mi] = *(const bf16x8*)(&lA[r * 32 + koff]);
    }
#pragma unroll
    for (int ni = 0; ni < NF; ++ni) {
      int r = wc * (NF * 16) + ni * 16 + (lane & 15);
      bfr[ni] = *(const bf16x8*)(&lB[r * 32 + koff]);
    }
#pragma unroll
    for (int mi = 0; mi < MF; ++mi)
#pragma unroll
      for (int ni = 0; ni < NF; ++ni)
        acc[mi][ni] = __builtin_amdgcn_mfma_f32_16x16x32_bf16(af[mi], bfr[ni], acc[mi][ni], 0, 0, 0);
    __syncthreads();
  }

  float* co = Cf + (size_t)blockIdx.z * (size_t)M * N;
  const int rbase = (lane >> 4) * 4;
  const int cbase = lane & 15;
#pragma unroll
  for (int mi = 0; mi < MF; ++mi) {
#pragma unroll
    for (int ni = 0; ni < NF; ++ni) {
      int row = m0 + wr * (MF * 16) + mi * 16 + rbase;
      int col = n0 + wc * (NF * 16) + ni * 16 + cbase;
      float bv = (EPI >= 2) ? bias[col] : 0.f;
#pragma unroll
      for (int r = 0; r < 4; ++r) {
        float v = acc[mi][ni][r] + bv;
        if (EPI == 2) v = fmaxf(v, 0.f);
        size_t idx = (size_t)(row + r) * N + col;
        if (EPI == 1 || EPI == 2) Cb[idx] = f2b(v);
        else co[idx] = v;
      }
    }
  }
}

// ---------------- causal depthwise conv(K=4) + silu ----------------
__global__ __launch_bounds__(256) void conv_silu_kernel(
    const u16* __restrict__ xz, const float* __restrict__ cw,
    const float* __restrict__ cb, float* __restrict__ xc, u16* __restrict__ xcb) {
  int idx = blockIdx.x * 256 + threadIdx.x;
  int d = idx & 1023;
  int t = (idx >> 10) & 1023;
  int token = idx >> 10;
  float4 w4 = *(const float4*)(cw + (size_t)d * 4);
  const float wk[4] = {w4.x, w4.y, w4.z, w4.w};
  float s = cb[d];
  const u16* xx = xz + (size_t)(token - t) * 2048 + d;
#pragma unroll
  for (int k = 0; k < 4; ++k) {
    int tt = t - 3 + k;
    if (tt >= 0) s += wk[k] * b2f(xx[(size_t)tt * 2048]);
  }
  float sl = s / (1.f + expf(-s));
  xc[idx] = sl;
  xcb[idx] = f2b(sl);
}

// ---------------- reduce x_proj partials + dt = softplus(dbc@dpwT + dpb) ----------------
__global__ __launch_bounds__(256) void dt_kernel2(
    const float* __restrict__ P, const float* __restrict__ dpwT,
    const float* __restrict__ dpb, float* __restrict__ dtout,
    float* __restrict__ dbcr) {
  const int tid = threadIdx.x;
  const int tok0 = blockIdx.x * 16;
  __shared__ float sm[16][64];
  const size_t str = (size_t)4096 * 64;
  for (int i = tid; i < 16 * 64; i += 256) {
    size_t o = (size_t)tok0 * 64 + i;
    float v = P[o] + P[str + o] + P[2 * str + o] + P[3 * str + o];
    ((float*)sm)[i] = v;
    dbcr[o] = v;
  }
  __syncthreads();
  float acc0[16], acc1[16], acc2[16], acc3[16];
#pragma unroll
  for (int t = 0; t < 16; ++t) { acc0[t] = 0.f; acc1[t] = 0.f; acc2[t] = 0.f; acc3[t] = 0.f; }
#pragma unroll 4
  for (int j = 0; j < 32; ++j) {
    float w0 = dpwT[(size_t)j * 1024 + tid];
    float w1 = dpwT[(size_t)j * 1024 + 256 + tid];
    float w2 = dpwT[(size_t)j * 1024 + 512 + tid];
    float w3 = dpwT[(size_t)j * 1024 + 768 + tid];
#pragma unroll
    for (int t = 0; t < 16; ++t) {
      float sv = sm[t][j];
      acc0[t] += sv * w0;
      acc1[t] += sv * w1;
      acc2[t] += sv * w2;
      acc3[t] += sv * w3;
    }
  }
  const float b0 = dpb[tid], b1 = dpb[256 + tid], b2 = dpb[512 + tid], b3 = dpb[768 + tid];
#pragma unroll
  for (int t = 0; t < 16; ++t) {
    size_t o = (size_t)(tok0 + t) * 1024 + tid;
    float a0 = acc0[t] + b0, a1 = acc1[t] + b1, a2 = acc2[t] + b2, a3 = acc3[t] + b3;
    dtout[o]       = (a0 > 20.f) ? a0 : logf(1.f + expf(a0));
    dtout[o + 256] = (a1 > 20.f) ? a1 : logf(1.f + expf(a1));
    dtout[o + 512] = (a2 > 20.f) ? a2 : logf(1.f + expf(a2));
    dtout[o + 768] = (a3 > 20.f) ? a3 : logf(1.f + expf(a3));
  }
}

// ---------------- chunked selective scan, lane-owns-d ----------------
// E/U/H0 layout: [b][c][n][d] (d innermost, coalesced).
__global__ __launch_bounds__(256) void scan1(
    const float* __restrict__ dt, const float* __restrict__ xc,
    const float* __restrict__ dbc, const float* __restrict__ Alog,
    float* __restrict__ Ebuf, float* __restrict__ Ubuf, int NCc, int TCc) {
  const int d = blockIdx.x * 256 + threadIdx.x;
  const int c = blockIdx.y;
  const int b = blockIdx.z;
  const int t0 = c * TCc;
  __shared__ __align__(16) float sB[64][16];
  for (int i = threadIdx.x; i < TCc * 16; i += 256) {
    int t = i >> 4, n = i & 15;
    sB[t][n] = dbc[((size_t)(b * 1024 + t0 + t)) * 64 + 32 + n];
  }
  float A2[16];
#pragma unroll
  for (int q = 0; q < 4; ++q) {
    float4 a4 = *(const float4*)(Alog + (size_t)d * 16 + q * 4);
    A2[q * 4 + 0] = -expf(a4.x) * 1.4426950408889634f;
    A2[q * 4 + 1] = -expf(a4.y) * 1.4426950408889634f;
    A2[q * 4 + 2] = -expf(a4.z) * 1.4426950408889634f;
    A2[q * 4 + 3] = -expf(a4.w) * 1.4426950408889634f;
  }
  __syncthreads();
  float hc[16];
#pragma unroll
  for (int n = 0; n < 16; ++n) hc[n] = 0.f;
  float sumdt = 0.f;
  size_t tok = (size_t)b * 1024 + t0;
  for (int t = 0; t < TCc; ++t, ++tok) {
    float dtv = dt[tok * 1024 + d];
    float xcv = xc[tok * 1024 + d];
    float du = dtv * xcv;
    sumdt += dtv;
#pragma unroll
    for (int q = 0; q < 4; ++q) {
      float4 B4 = *(const float4*)(&sB[t][q * 4]);
      float e0 = exp2f(dtv * A2[q * 4 + 0]);
      float e1 = exp2f(dtv * A2[q * 4 + 1]);
      float e2 = exp2f(dtv * A2[q * 4 + 2]);
      float e3 = exp2f(dtv * A2[q * 4 + 3]);
      hc[q * 4 + 0] = e0 * hc[q * 4 + 0] + du * B4.x;
      hc[q * 4 + 1] = e1 * hc[q * 4 + 1] + du * B4.y;
      hc[q * 4 + 2] = e2 * hc[q * 4 + 2] + du * B4.z;
      hc[q * 4 + 3] = e3 * hc[q * 4 + 3] + du * B4.w;
    }
  }
  size_t ob = (((size_t)b * NCc + c) * 16) * 1024 + d;
#pragma unroll
  for (int n = 0; n < 16; ++n) {
    Ebuf[ob + (size_t)n * 1024] = exp2f(A2[n] * sumdt);
    Ubuf[ob + (size_t)n * 1024] = hc[n];
  }
}

// prefix-scan chunk summaries -> per-chunk initial state H0[b][c][n][d]
__global__ __launch_bounds__(256) void scan_mid(
    const float* __restrict__ Ebuf, const float* __restrict__ Ubuf,
    float* __restrict__ H0, int NCc) {
  int idx = blockIdx.x * 256 + threadIdx.x;   // b*16384 + n*1024 + d
  int b = idx >> 14;
  int nd = idx & 16383;
  float h = 0.f;
  size_t o0 = ((size_t)b * NCc * 16) * 1024 + nd;
  const size_t cstr = (size_t)16 * 1024;
  for (int cc = 0; cc < NCc; ++cc) {
    size_t o = o0 + (size_t)cc * cstr;
    H0[o] = h;
    if (cc < NCc - 1) h = Ebuf[o] * h + Ubuf[o];
  }
}

__global__ __launch_bounds__(256) void scan2(
    const float* __restrict__ dt, const float* __restrict__ xc,
    const float* __restrict__ dbc, const u16* __restrict__ xz,
    const float* __restrict__ Alog, const float* __restrict__ Dp,
    const float* __restrict__ H0, u16* __restrict__ yg, int NCc, int TCc) {
  const int d = blockIdx.x * 256 + threadIdx.x;
  const int c = blockIdx.y;
  const int b = blockIdx.z;
  const int t0 = c * TCc;
  __shared__ __align__(16) float sB[64][16];
  __shared__ __align__(16) float sC[64][16];
  for (int i = threadIdx.x; i < TCc * 16; i += 256) {
    int t = i >> 4, n = i & 15;
    size_t o = ((size_t)(b * 1024 + t0 + t)) * 64 + 32;
    sB[t][n] = dbc[o + n];
    sC[t][n] = dbc[o + 16 + n];
  }
  float A2[16];
#pragma unroll
  for (int q = 0; q < 4; ++q) {
    float4 a4 = *(const float4*)(Alog + (size_t)d * 16 + q * 4);
    A2[q * 4 + 0] = -expf(a4.x) * 1.4426950408889634f;
    A2[q * 4 + 1] = -expf(a4.y) * 1.4426950408889634f;
    A2[q * 4 + 2] = -expf(a4.z) * 1.4426950408889634f;
    A2[q * 4 + 3] = -expf(a4.w) * 1.4426950408889634f;
  }
  const float Dd = Dp[d];
  float hc[16];
  size_t ob = (((size_t)b * NCc + c) * 16) * 1024 + d;
#pragma unroll
  for (int n = 0; n < 16; ++n) hc[n] = H0[ob + (size_t)n * 1024];
  __syncthreads();
  size_t tok = (size_t)b * 1024 + t0;
  for (int t = 0; t < TCc; ++t, ++tok) {
    float dtv = dt[tok * 1024 + d];
    float xcv = xc[tok * 1024 + d];
    float du = dtv * xcv;
    float y0 = 0.f, y1 = 0.f, y2 = 0.f, y3 = 0.f;
#pragma unroll
    for (int q = 0; q < 4; ++q) {
      float4 B4 = *(const float4*)(&sB[t][q * 4]);
      float4 C4 = *(const float4*)(&sC[t][q * 4]);
      float e0 = exp2f(dtv * A2[q * 4 + 0]);
      float e1 = exp2f(dtv * A2[q * 4 + 1]);
      float e2 = exp2f(dtv * A2[q * 4 + 2]);
      float e3 = exp2f(dtv * A2[q * 4 + 3]);
      hc[q * 4 + 0] = e0 * hc[q * 4 + 0] + du * B4.x;
      hc[q * 4 + 1] = e1 * hc[q * 4 + 1] + du * B4.y;
      hc[q * 4 + 2] = e2 * hc[q * 4 + 2] + du * B4.z;
      hc[q * 4 + 3] = e3 * hc[q * 4 + 3] + du * B4.w;
      y0 += hc[q * 4 + 0] * C4.x;
      y1 += hc[q * 4 + 1] * C4.y;
      y2 += hc[q * 4 + 2] * C4.z;
      y3 += hc[q * 4 + 3] * C4.w;
    }
    float y = (y0 + y1) + (y2 + y3);
    float z = b2f(xz[tok * 2048 + 1024 + d]);
    float g = z / (1.f + expf(-z));
    yg[tok * 1024 + d] = f2b((y + Dd * xcv) * g);
  }
}

// ---------------- reward head: out = t1r @ ro_w2^T + b (N=1) ----------------
__global__ __launch_bounds__(256) void reward_head_kernel(
    const u16* __restrict__ t1r, const float* __restrict__ w2,
    const float* __restrict__ b2, float* __restrict__ outr) {
  int tok = blockIdx.x * 4 + (threadIdx.x >> 6);
  int lane = threadIdx.x & 63;
  float s = 0.f;
#pragma unroll
  for (int j = 0; j < 256; j += 64) s += b2f(t1r[(size_t)tok * 256 + j + lane]) * w2[j + lane];
#pragma unroll
  for (int o = 32; o; o >>= 1) s += __shfl_xor(s, o);
  if (lane == 0) outr[tok] = s + b2[0];
}

extern "C" void kernel_launch(void* const* d_in, const int* in_sizes, int n_in,
                              void* d_out, int out_size, void* d_ws, size_t ws_size,
                              hipStream_t stream) {
  const float* x    = (const float*)d_in[0];
  const float* rtg  = (const float*)d_in[1];
  const float* Wse  = (const float*)d_in[2];
  const float* bse  = (const float*)d_in[3];
  const float* Wre  = (const float*)d_in[4];
  const float* bre  = (const float*)d_in[5];
  const float* lnw  = (const float*)d_in[6];
  const float* lnb  = (const float*)d_in[7];
  const float* ipw  = (const float*)d_in[8];
  const float* cw   = (const float*)d_in[9];
  const float* cb   = (const float*)d_in[10];
  const float* xpw  = (const float*)d_in[11];
  const float* dpw  = (const float*)d_in[12];
  const float* dpb  = (const float*)d_in[13];
  const float* Alog = (const float*)d_in[14];
  const float* Dp   = (const float*)d_in[15];
  const float* opw  = (const float*)d_in[16];
  const float* nw   = (const float*)d_in[17];
  const float* nfw  = (const float*)d_in[18];
  const float* sow1 = (const float*)d_in[19];
  const float* sob1 = (const float*)d_in[20];
  const float* sow2 = (const float*)d_in[21];
  const float* sob2 = (const float*)d_in[22];
  const float* row1 = (const float*)d_in[23];
  const float* rob1 = (const float*)d_in[24];
  const float* row2 = (const float*)d_in[25];
  const float* rob2 = (const float*)d_in[26];
  (void)in_sizes; (void)n_in; (void)out_size;

  char* wsp = (char*)d_ws;
  size_t off = 0;
  auto alloc = [&](size_t bytes) -> void* {
    off = (off + 255) & ~(size_t)255;
    void* p = wsp + off;
    off += bytes;
    return p;
  };
  const int TOK = 4096;
  float* h     = (float*)alloc((size_t)TOK * 512 * 4);
  float* resid = (float*)alloc((size_t)TOK * 512 * 4);
  u16* hn      = (u16*)alloc((size_t)TOK * 512 * 2);
  u16* xzb     = (u16*)alloc((size_t)TOK * 2048 * 2);
  float* xcf   = (float*)alloc((size_t)TOK * 1024 * 4);
  u16* xcb     = (u16*)alloc((size_t)TOK * 1024 * 2);
  float* dbcP  = (float*)alloc((size_t)4 * TOK * 64 * 4);   // x_proj K-split partials
  float* dbc   = (float*)alloc((size_t)TOK * 64 * 4);       // reduced
  float* dtf   = (float*)alloc((size_t)TOK * 1024 * 4);
  float* PEt   = (float*)alloc((size_t)1024 * 512 * 4);
  float* dpwT  = (float*)alloc((size_t)4 * 32 * 1024 * 4);
  u16* ipwb    = (u16*)alloc((size_t)4 * 2048 * 512 * 2);
  u16* xpwb    = (u16*)alloc((size_t)4 * 64 * 1024 * 2);
  u16* opwb    = (u16*)alloc((size_t)4 * 512 * 1024 * 2);
  u16* sow1b   = (u16*)alloc((size_t)256 * 512 * 2);
  u16* sow2b   = (u16*)alloc((size_t)128 * 256 * 2);
  u16* row1b   = (u16*)alloc((size_t)256 * 512 * 2);

  // pick NC by available workspace (deterministic in ws_size -> graph-safe)
  // need: E/U = 2*4*NC*16*1024*4 B, H0 = 4*NC*16*1024*4 B
  size_t base_off = (off + 255) & ~(size_t)255;
  auto scan_bytes = [](int nc) {
    return (size_t)3 * 4 * nc * 16 * 1024 * 4 + 512;
  };
  int NCc = 16;
  if (ws_size >= base_off + scan_bytes(64)) NCc = 64;
  else if (ws_size >= base_off + scan_bytes(32)) NCc = 32;
  int TCc = 1024 / NCc;
  // E/U (scan chunk state) aliased with t1s/t1r (head temporaries).
  char* shared8 = (char*)alloc((size_t)2 * 4096 * NCc * 16 * 4);
  float* Ebuf  = (float*)shared8;
  float* Ubuf  = Ebuf + (size_t)4096 * NCc * 16;
  float* H0    = (float*)alloc((size_t)4096 * NCc * 16 * 4);
  u16* t1s     = (u16*)shared8;
  u16* t1r     = t1s + (size_t)TOK * 256;

  auto cvt = [&](const float* src, u16* dst, int n) {
    f2b_kernel<<<(n + 255) / 256, 256, 0, stream>>>(src, dst, n);
  };
  cvt(ipw, ipwb, 4 * 2048 * 512);
  cvt(xpw, xpwb, 4 * 64 * 1024);
  cvt(opw, opwb, 4 * 512 * 1024);
  cvt(sow1, sow1b, 256 * 512);
  cvt(sow2, sow2b, 128 * 256);
  cvt(row1, row1b, 256 * 512);

  pe_kernel<<<1024, 256, 0, stream>>>(PEt);
  dpw_t_kernel<<<dim3(128, 4), 256, 0, stream>>>(dpw, dpwT);
  embed_ln2<<<256, 256, 0, stream>>>(x, rtg, Wse, bse, Wre, bre, lnw, lnb, PEt, h);

  for (int i = 0; i < 4; ++i) {
    resid_rms_kernel<<<TOK, 256, 0, stream>>>(h, resid, nw + i * 512, hn, i == 0);
    gemm_bt<128, 128, 2, 2, 1><<<dim3(32, 16, 1), 256, 0, stream>>>(
        hn, ipwb + (size_t)i * 2048 * 512, nullptr, xzb, nullptr, 4096, 2048, 512);
    conv_silu_kernel<<<TOK * 1024 / 256, 256, 0, stream>>>(
        xzb, cw + (size_t)i * 4096, cb + i * 1024, xcf, xcb);
    gemm_bt<128, 64, 2, 2, 0><<<dim3(32, 1, 4), 256, 0, stream>>>(
        xcb, xpwb + (size_t)i * 64 * 1024, dbcP, nullptr, nullptr, 4096, 64, 1024);
    dt_kernel2<<<TOK / 16, 256, 0, stream>>>(dbcP, dpwT + (size_t)i * 32 * 1024,
                                             dpb + i * 1024, dtf, dbc);
    scan1<<<dim3(4, NCc - 1, 4), 256, 0, stream>>>(
        dtf, xcf, dbc, Alog + (size_t)i * 1024 * 16, Ebuf, Ubuf, NCc, TCc);
    scan_mid<<<256, 256, 0, stream>>>(Ebuf, Ubuf, H0, NCc);
    scan2<<<dim3(4, NCc, 4), 256, 0, stream>>>(
        dtf, xcf, dbc, xzb, Alog + (size_t)i * 1024 * 16, Dp + i * 1024,
        H0, xcb, NCc, TCc);
    gemm_bt<128, 64, 2, 2, 0><<<dim3(32, 8, 1), 256, 0, stream>>>(
        xcb, opwb + (size_t)i * 512 * 1024, h, nullptr, nullptr, 4096, 512, 1024);
  }

  resid_rms_kernel<<<TOK, 256, 0, stream>>>(h, resid, nfw, hn, 0);
  gemm_bt<64, 64, 2, 2, 2><<<dim3(64, 4, 1), 256, 0, stream>>>(
      hn, sow1b, nullptr, t1s, sob1, 4096, 256, 512);
  gemm_bt<64, 64, 2, 2, 3><<<dim3(64, 2, 1), 256, 0, stream>>>(
      t1s, sow2b, (float*)d_out, nullptr, sob2, 4096, 128, 256);
  gemm_bt<64, 64, 2, 2, 2><<<dim3(64, 4, 1), 256, 0, stream>>>(
      hn, row1b, nullptr, t1r, rob1, 4096, 256, 512);
  reward_head_kernel<<<TOK / 4, 256, 0, stream>>>(
      t1r, row2, rob2, (float*)d_out + (size_t)TOK * 128);
}